// Round 1
// baseline (259.848 us; speedup 1.0000x reference)
//
#include <hip/hip_runtime.h>

// ---------------------------------------------------------------------------
// Q_DenseLayer: BN-fold int8 affine -> ReLU -> per-tensor 8b quant ->
// int8 3x3 conv (MFMA i32_16x16x64_i8) -> per-tensor 8b requant.
// Shapes: x[32,512,32,32] f32, W[128,512,3,3] f32, out y[32,128,32,32] + s_out.
//
// R9: fuse final requant into k_conv via a hand-rolled grid barrier.
// k_conv's 512 blocks are all co-resident (__launch_bounds__(256,2): 2
// blocks/CU x 256 CU, LDS 72KB*2<=160KB), so: compute block absmax from the
// accumulators in registers -> atomicMax -> grid barrier (counter ws_u[2],
// zeroed by k_prep, bounded spin => cannot hang) -> requant in-register ->
// write y ONCE. Removes k_yquant (33.6 MB y round-trip + 1 launch).
// R8 retained: k_conv stages weights through LDS (global_load_lds width=16),
// 4 waves = 2 row-pairs x 2 K-halves sharing one 64-co B tile. R6/R7 layouts:
//   x2 [b][h][ci8][cq4][w'34][16B], wq [tap][ci][cq4][co128][16B].
// Fixed ~95us of timed harness work (256MiB ws poison + d_in restore) is
// outside our control; controllable kernel budget ~65us.
// ---------------------------------------------------------------------------

typedef int v4i __attribute__((ext_vector_type(4)));

// workspace byte offsets
#define WS_A1    64        // 512 f: A1_c = w_int*bn_sf/s_in
#define WS_B1    2112      // 512 f: B1_c = b_int*bn_sf
#define WS_WSC   4160      // 128 f
#define WS_XMX   4672      // 512 f: per-channel max(x)
#define WS_XMN   6720      // 512 f: per-channel min(x)
#define WS_WQ    8768      // 589824 i8: [tap][ci][cq][co128][16]
#define WS_X2    598592    // 17825792 u8: [b][h][ci][cq][w'34][16]
#define WS_ZROW  18424384  // 17408 u8 zero row
// ws_f[3] = s_act (k_xquant blk0), ws_u[1] = absmax(y) bits, ws_u[2] = barrier

__device__ __forceinline__ float wave_max(float m) {
#pragma unroll
    for (int off = 32; off; off >>= 1) m = fmaxf(m, __shfl_xor(m, off));
    return m;
}

// async global->LDS, 16B per lane: per-lane gsrc, wave-uniform LDS base
__device__ __forceinline__ void stage16(const char* g, char* s, int lane) {
#if defined(__has_builtin) && __has_builtin(__builtin_amdgcn_global_load_lds)
    __builtin_amdgcn_global_load_lds(
        (const __attribute__((address_space(1))) void*)g,
        (__attribute__((address_space(3))) void*)s, 16, 0, 0);
#else
    *(v4i*)(s + lane * 16) = *(const v4i*)g;
#endif
}

// ---- kernel 1: fused prep ---------------------------------------------------
// blocks 0..511:   per-channel x max/min (block c owns channel c)
// blocks 512..639: conv-weight quant (co = bid-512)
// block 640:       BN fold -> A1/B1, zero y-absmax + grid-barrier counter
__global__ __launch_bounds__(512) void k_prep(
    const float* __restrict__ gamma, const float* __restrict__ beta,
    const float* __restrict__ mean,  const float* __restrict__ var,
    const float* __restrict__ asf,   const float* __restrict__ cw,
    const float4* __restrict__ x4,
    float* ws_f, unsigned* ws_u, float* __restrict__ wsc,
    signed char* __restrict__ wq) {
    int t = threadIdx.x;
    int bid = blockIdx.x;
    __shared__ float red[16];
    if (bid < 512) {
        int c = bid;
        float mx = -3.4e38f, mn = 3.4e38f;
#pragma unroll
        for (int r = 0; r < 16; ++r) {
            int bbb = r * 2 + (t >> 8);
            float4 v = x4[((size_t)(bbb * 512 + c)) * 256 + (t & 255)];
            mx = fmaxf(mx, fmaxf(fmaxf(v.x, v.y), fmaxf(v.z, v.w)));
            mn = fminf(mn, fminf(fminf(v.x, v.y), fminf(v.z, v.w)));
        }
        mx = wave_max(mx);
        mn = -wave_max(-mn);
        if ((t & 63) == 0) { red[t >> 6] = mx; red[8 + (t >> 6)] = mn; }
        __syncthreads();
        if (t == 0) {
            float M = red[0], N = red[8];
#pragma unroll
            for (int i = 1; i < 8; ++i) { M = fmaxf(M, red[i]); N = fminf(N, red[8 + i]); }
            ws_f[WS_XMX / 4 + c] = M;
            ws_f[WS_XMN / 4 + c] = N;
        }
    } else if (bid < 640) {
        int co = bid - 512;
        const float* w = cw + (size_t)co * 4608;
        float m = 0.f;
        for (int j = t; j < 4608; j += 512) m = fmaxf(m, fabsf(w[j]));
        m = wave_max(m);
        if ((t & 63) == 0) red[t >> 6] = m;
        __syncthreads();
        float mall = red[0];
#pragma unroll
        for (int i = 1; i < 8; ++i) mall = fmaxf(mall, red[i]);
        float sc = mall / 127.0f;
        if (t == 0) wsc[co] = sc;
        int ci = t >> 6, cq = (t >> 4) & 3, cb = t & 15;
#pragma unroll
        for (int tap = 0; tap < 9; ++tap) {
            float q = fminf(fmaxf(rintf(w[t * 9 + tap] / sc), -128.f), 127.f);
            wq[(((size_t)(tap * 8 + ci) * 4 + cq) * 128 + co) * 16 + cb] = (signed char)q;
        }
    } else {
        float wbn = gamma[t] / sqrtf(var[t] + 1e-5f);
        float bbn = beta[t] - mean[t] * wbn;
        float m = wave_max(fabsf(wbn));
        if ((t & 63) == 0) red[t >> 6] = m;
        __syncthreads();
        float mall = red[0];
#pragma unroll
        for (int i = 1; i < 8; ++i) mall = fmaxf(mall, red[i]);
        float ws_bn = mall / 127.0f;
        float s_in  = asf[0];
        float bn_sf = ws_bn * s_in;
        float wint  = fminf(fmaxf(rintf(wbn / ws_bn), -128.f), 127.f);
        float bint  = rintf(bbn / bn_sf);
        ws_f[WS_A1 / 4 + t] = wint * bn_sf / s_in;  // x1 = fmaf(x, A1, B1)
        ws_f[WS_B1 / 4 + t] = bint * bn_sf;
        if (t == 0) { ws_u[1] = 0u; ws_u[2] = 0u; }  // absmax(y) bits, barrier
    }
}

// ---- kernel 2: quantize x to int8 [ci][cq][w'][16] halo layout -------------
__global__ __launch_bounds__(256) void k_xquant(
    const float4* __restrict__ x4, float* __restrict__ ws_f,
    unsigned* __restrict__ x2u, unsigned* __restrict__ zrowu) {
    int bb = 31 - (blockIdx.x >> 5), h = blockIdx.x & 31;
    const float* A1 = ws_f + WS_A1 / 4;
    const float* B1 = ws_f + WS_B1 / 4;
    const float* XMX = ws_f + WS_XMX / 4;
    const float* XMN = ws_f + WS_XMN / 4;
    int t = threadIdx.x;

    // s_act from per-channel stats (exact: fma monotone in x, relu clamp >=0)
    __shared__ float sred[4];
    float cand = 0.f;
#pragma unroll
    for (int c0 = 0; c0 < 512; c0 += 256) {
        int c = c0 + t;
        float A = A1[c], B = B1[c];
        cand = fmaxf(cand, fmaxf(fmaf(XMX[c], A, B), fmaf(XMN[c], A, B)));
    }
    cand = wave_max(cand);
    if ((t & 63) == 0) sred[t >> 6] = cand;
    __syncthreads();
    float xm = fmaxf(fmaxf(sred[0], sred[1]), fmaxf(sred[2], sred[3]));
    float inv_sact = 127.0f / xm;
    if (blockIdx.x == 0 && t == 0) ws_f[3] = xm / 127.0f;  // s_act for k_conv

    size_t rowd = (size_t)(bb * 32 + h) * 4352;  // dwords per (b,h) row
    // zero halo columns w'=0,33
    {
        int p = t >> 3, side = (t >> 2) & 1, d = t & 3;
        x2u[rowd + (p * 34 + side * 33) * 4 + d] = 0u;
    }
    if (blockIdx.x < 17) {
        int idx = blockIdx.x * 256 + t;
        if (idx < 4352) zrowu[idx] = 0u;
    }

    __shared__ unsigned lds[512 * 9];  // [c][w4(8)] packed bytes, +1 pad

#pragma unroll
    for (int it = 0; it < 16; ++it) {
        int idx = it * 256 + t;
        int c = idx >> 3, f4 = idx & 7;
        float4 v = x4[((size_t)bb * 512 + c) * 256 + h * 8 + f4];
        float A = A1[c] * inv_sact, B = B1[c] * inv_sact;
        unsigned q0 = (unsigned)(int)fminf(rintf(fmaxf(fmaf(v.x, A, B), 0.f)), 127.f);
        unsigned q1 = (unsigned)(int)fminf(rintf(fmaxf(fmaf(v.y, A, B), 0.f)), 127.f);
        unsigned q2 = (unsigned)(int)fminf(rintf(fmaxf(fmaf(v.z, A, B), 0.f)), 127.f);
        unsigned q3 = (unsigned)(int)fminf(rintf(fmaxf(fmaf(v.w, A, B), 0.f)), 127.f);
        lds[c * 9 + f4] = q0 | (q1 << 8) | (q2 << 16) | (q3 << 24);
    }
    __syncthreads();

#pragma unroll
    for (int it = 0; it < 4; ++it) {
        int p = it * 8 + (t >> 5);   // 0..31 = ci*4+cq
        int s = (t >> 2) & 7;        // w4 group
        int k = t & 3;               // w = s*4+k, w' = w+1
        unsigned L[16];
#pragma unroll
        for (int j = 0; j < 16; ++j) L[j] = lds[(p * 16 + j) * 9 + s];
        uint4 o;
        unsigned* op = (unsigned*)&o;
#pragma unroll
        for (int d = 0; d < 4; ++d)
            op[d] = ((L[4 * d] >> (8 * k)) & 255u) |
                    (((L[4 * d + 1] >> (8 * k)) & 255u) << 8) |
                    (((L[4 * d + 2] >> (8 * k)) & 255u) << 16) |
                    (((L[4 * d + 3] >> (8 * k)) & 255u) << 24);
        *(uint4*)(x2u + rowd + (size_t)(p * 34 + s * 4 + 1 + k) * 4) = o;
    }
}

// ---- kernel 3: int8 3x3 conv + fused final requant ------------------------
// block = 4 waves = (rp in {0,1} row-pairs) x (kv in {0,1} K-halves), 64 co.
// grid 512 (XCD-swizzled), 2 blocks/CU => ALL blocks co-resident, enabling
// the grid barrier for the global absmax(y) reduction. LDS 72KB: B stage
// (2 ci-slots of 36KB), reused as K-combine buffer (32KB) after main loop.
__global__ __launch_bounds__(256, 2) void k_conv(
    const unsigned char* __restrict__ x2, const unsigned char* __restrict__ zrow,
    const signed char* __restrict__ wq,
    const float* __restrict__ wsc, const float* __restrict__ ws_f,
    unsigned* __restrict__ ws_u, float* __restrict__ y) {
    __shared__ char ldsb[73728];
    int t = threadIdx.x;
    int lane = t & 63, wv = t >> 6;
    int kv = wv & 1, rp = wv >> 1;
    int m = lane & 15, quad = lane >> 4;

    int bid = blockIdx.x;
    int tile = (bid & 7) * 64 + (bid >> 3);  // XCD swizzle, 64 tiles/XCD
    int ch = tile & 1;
    int rg = (tile >> 1) & 7;                // row-group of 4 rows
    int bb = tile >> 4;
    int co0 = ch * 64;
    int h0 = rg * 4 + rp * 2;                // this wave's first output row

    const unsigned char* xb = x2 + (size_t)bb * (32 * 17408);
    const v4i* rpt[4];
#pragma unroll
    for (int j = 0; j < 4; ++j) {
        int row = h0 - 1 + j;
        rpt[j] = (const v4i*)(((unsigned)row < 32u) ? (xb + (size_t)row * 17408) : zrow);
    }

    v4i acc[4][4];
#pragma unroll
    for (int i = 0; i < 4; ++i)
#pragma unroll
        for (int j = 0; j < 4; ++j) acc[i][j] = (v4i){0, 0, 0, 0};

    int abase = quad * 34 + m;

    for (int j = 0; j < 4; ++j) {
        // stage B for ci = j (kv0 slot) and ci = 4+j (kv1 slot): 72 chunks of
        // 1KB, 18 per wave. chunk c -> (kvs, tap, cq).
#pragma unroll
        for (int i = 0; i < 18; ++i) {
            int c = wv * 18 + i;
            int kvs = (c >= 36) ? 1 : 0;
            int rem = c - kvs * 36;
            int tap = rem >> 2, cq = rem & 3;
            int ci = kvs * 4 + j;
            const char* g = (const char*)wq +
                ((((size_t)(tap * 8 + ci) * 4 + cq) * 128 + co0) * 16) + lane * 16;
            char* s = ldsb + (((kvs * 9 + tap) * 4 + cq) << 10);
            stage16(g, s, lane);
        }
        __syncthreads();

        int ci = kv * 4 + j;
        const v4i* bbase = (const v4i*)ldsb + kv * 2304;  // 9*4*64 v4i per slot
#pragma unroll
        for (int kh = 0; kh < 3; ++kh)
#pragma unroll
            for (int kw = 0; kw < 3; ++kw) {
                int tap = kh * 3 + kw;
                v4i a[4];
#pragma unroll
                for (int mt = 0; mt < 4; ++mt)
                    a[mt] = rpt[kh + (mt >> 1)][ci * 136 + abase + kw + (mt & 1) * 16];
#pragma unroll
                for (int nt = 0; nt < 4; ++nt) {
                    v4i bf = bbase[(tap * 4 + quad) * 64 + nt * 16 + m];
#pragma unroll
                    for (int mt = 0; mt < 4; ++mt)
                        acc[mt][nt] = __builtin_amdgcn_mfma_i32_16x16x64_i8(a[mt], bf, acc[mt][nt], 0, 0, 0);
                }
            }
        __syncthreads();
    }

    // K-combine: kv=1 waves publish, kv=0 waves add (reuse stage LDS, 32KB)
    v4i* red = (v4i*)ldsb;
    if (kv == 1) {
#pragma unroll
        for (int mt = 0; mt < 4; ++mt)
#pragma unroll
            for (int nt = 0; nt < 4; ++nt)
                red[((rp * 16 + mt * 4 + nt) << 6) + lane] = acc[mt][nt];
    }
    __syncthreads();

    float s_act = ws_f[3];
    if (kv == 0) {
        float mx = 0.f;
#pragma unroll
        for (int nt = 0; nt < 4; ++nt) {
            float sf = s_act * wsc[co0 + nt * 16 + m];
#pragma unroll
            for (int mt = 0; mt < 4; ++mt) {
                v4i p = red[((rp * 16 + mt * 4 + nt) << 6) + lane];
                acc[mt][nt].x += p.x; acc[mt][nt].y += p.y;
                acc[mt][nt].z += p.z; acc[mt][nt].w += p.w;
                mx = fmaxf(mx, fmaxf(
                    fmaxf(fabsf((float)acc[mt][nt].x * sf), fabsf((float)acc[mt][nt].y * sf)),
                    fmaxf(fabsf((float)acc[mt][nt].z * sf), fabsf((float)acc[mt][nt].w * sf))));
            }
        }
        mx = wave_max(mx);
        if (lane == 0) atomicMax(ws_u + 1, __float_as_uint(mx));
    }

    // ---- grid barrier (all 512 blocks resident by launch-bounds math).
    // Bounded spin (~1s worth) guarantees termination even if the residency
    // assumption is ever violated (would then fail verification, not hang).
    __syncthreads();
    if (t == 0) {
        __hip_atomic_fetch_add(ws_u + 2, 1u, __ATOMIC_ACQ_REL, __HIP_MEMORY_SCOPE_AGENT);
        int guard = 0;
        while (__hip_atomic_load(ws_u + 2, __ATOMIC_ACQUIRE, __HIP_MEMORY_SCOPE_AGENT) < 512u
               && ++guard < (1 << 24))
            __builtin_amdgcn_s_sleep(2);
    }
    __syncthreads();

    if (kv == 0) {
        // epilogue: requant in-register, write y ONCE.
        // C layout col(lane&15)=co, row(quad*4+reg)=w
        float s_out = __uint_as_float(
            __hip_atomic_load(ws_u + 1, __ATOMIC_ACQUIRE, __HIP_MEMORY_SCOPE_AGENT)) / 127.0f;
#pragma unroll
        for (int nt = 0; nt < 4; ++nt) {
            int co = co0 + nt * 16 + m;
            float sf = s_act * wsc[co];
#pragma unroll
            for (int mt = 0; mt < 4; ++mt) {
                int row = h0 + (mt >> 1);
                float* yb = y + ((size_t)(bb * 128 + co)) * 1024 + row * 32 + (mt & 1) * 16;
                float4 vv;
                vv.x = (float)acc[mt][nt][0] * sf;
                vv.y = (float)acc[mt][nt][1] * sf;
                vv.z = (float)acc[mt][nt][2] * sf;
                vv.w = (float)acc[mt][nt][3] * sf;
                vv.x = fminf(fmaxf(rintf(vv.x / s_out), -128.f), 127.f) * s_out;
                vv.y = fminf(fmaxf(rintf(vv.y / s_out), -128.f), 127.f) * s_out;
                vv.z = fminf(fmaxf(rintf(vv.z / s_out), -128.f), 127.f) * s_out;
                vv.w = fminf(fmaxf(rintf(vv.w / s_out), -128.f), 127.f) * s_out;
                *(float4*)(yb + quad * 4) = vv;
            }
        }
        if (blockIdx.x == 0 && t == 0) y[4194304] = s_out;
    }
}

extern "C" void kernel_launch(void* const* d_in, const int* in_sizes, int n_in,
                              void* d_out, int out_size, void* d_ws, size_t ws_size,
                              hipStream_t stream) {
    const float* x     = (const float*)d_in[0];
    const float* asf   = (const float*)d_in[1];
    const float* gamma = (const float*)d_in[2];
    const float* beta  = (const float*)d_in[3];
    const float* mean  = (const float*)d_in[4];
    const float* var   = (const float*)d_in[5];
    const float* cw    = (const float*)d_in[6];

    float*    ws_f = (float*)d_ws;
    unsigned* ws_u = (unsigned*)d_ws;
    signed char*   wq   = (signed char*)d_ws + WS_WQ;
    unsigned char* x2   = (unsigned char*)d_ws + WS_X2;
    unsigned char* zrow = (unsigned char*)d_ws + WS_ZROW;
    float* y = (float*)d_out;

    k_prep<<<641, 512, 0, stream>>>(gamma, beta, mean, var, asf, cw,
                                    (const float4*)x, ws_f, ws_u,
                                    ws_f + WS_WSC / 4, wq);
    k_xquant<<<1024, 256, 0, stream>>>((const float4*)x, ws_f,
                                       (unsigned*)x2, (unsigned*)zrow);
    k_conv<<<512, 256, 0, stream>>>(x2, zrow, wq, ws_f + WS_WSC / 4,
                                    ws_f, ws_u, y);
}

// Round 2
// 194.054 us; speedup vs baseline: 1.3390x; 1.3390x over previous
//
#include <hip/hip_runtime.h>

// ---------------------------------------------------------------------------
// Q_DenseLayer: BN-fold int8 affine -> ReLU -> per-tensor 8b quant ->
// int8 3x3 conv (MFMA i32_16x16x64_i8) -> per-tensor 8b requant.
// Shapes: x[32,512,32,32] f32, W[128,512,3,3] f32, out y[32,128,32,32] + s_out.
//
// R10: fix R9's grid-barrier regression. R9 polled with ACQUIRE/AGENT loads:
// each poll emits a cache-invalidate, and early-finished blocks invalidated
// their XCD's *shared* L2 millions of times, thrashing still-running blocks
// (k_conv 35 -> 88-119us, hbm collapsed). Fix: poll with RELAXED SYSTEM-scope
// loads (sc0+sc1 cache-bypass, reads the memory-side coherence point: always
// fresh, NO cache maintenance) + s_sleep(8). Counter add keeps ACQ_REL so the
// preceding atomicMax is drained (syncthreads vmcnt(0)) and globally visible
// before the count; s_out is read post-barrier with a relaxed system load.
// Residency for the barrier is empirically confirmed by R9 (spin resolved).
// R9 structure retained: requant fused into k_conv, y written ONCE, no
// k_yquant. R8 retained: B staged via global_load_lds, 4 waves = 2 row-pairs
// x 2 K-halves. Layouts: x2 [b][h][ci8][cq4][w'34][16B],
// wq [tap][ci][cq4][co128][16B]. Fixed ~95us harness work outside our control.
// ---------------------------------------------------------------------------

typedef int v4i __attribute__((ext_vector_type(4)));

// workspace byte offsets
#define WS_A1    64        // 512 f: A1_c = w_int*bn_sf/s_in
#define WS_B1    2112      // 512 f: B1_c = b_int*bn_sf
#define WS_WSC   4160      // 128 f
#define WS_XMX   4672      // 512 f: per-channel max(x)
#define WS_XMN   6720      // 512 f: per-channel min(x)
#define WS_WQ    8768      // 589824 i8: [tap][ci][cq][co128][16]
#define WS_X2    598592    // 17825792 u8: [b][h][ci][cq][w'34][16]
#define WS_ZROW  18424384  // 17408 u8 zero row
// ws_f[3] = s_act (k_xquant blk0), ws_u[1] = absmax(y) bits, ws_u[2] = barrier

__device__ __forceinline__ float wave_max(float m) {
#pragma unroll
    for (int off = 32; off; off >>= 1) m = fmaxf(m, __shfl_xor(m, off));
    return m;
}

// async global->LDS, 16B per lane: per-lane gsrc, wave-uniform LDS base
__device__ __forceinline__ void stage16(const char* g, char* s, int lane) {
#if defined(__has_builtin) && __has_builtin(__builtin_amdgcn_global_load_lds)
    __builtin_amdgcn_global_load_lds(
        (const __attribute__((address_space(1))) void*)g,
        (__attribute__((address_space(3))) void*)s, 16, 0, 0);
#else
    *(v4i*)(s + lane * 16) = *(const v4i*)g;
#endif
}

// ---- kernel 1: fused prep ---------------------------------------------------
// blocks 0..511:   per-channel x max/min (block c owns channel c)
// blocks 512..639: conv-weight quant (co = bid-512)
// block 640:       BN fold -> A1/B1, zero y-absmax + grid-barrier counter
__global__ __launch_bounds__(512) void k_prep(
    const float* __restrict__ gamma, const float* __restrict__ beta,
    const float* __restrict__ mean,  const float* __restrict__ var,
    const float* __restrict__ asf,   const float* __restrict__ cw,
    const float4* __restrict__ x4,
    float* ws_f, unsigned* ws_u, float* __restrict__ wsc,
    signed char* __restrict__ wq) {
    int t = threadIdx.x;
    int bid = blockIdx.x;
    __shared__ float red[16];
    if (bid < 512) {
        int c = bid;
        float mx = -3.4e38f, mn = 3.4e38f;
#pragma unroll
        for (int r = 0; r < 16; ++r) {
            int bbb = r * 2 + (t >> 8);
            float4 v = x4[((size_t)(bbb * 512 + c)) * 256 + (t & 255)];
            mx = fmaxf(mx, fmaxf(fmaxf(v.x, v.y), fmaxf(v.z, v.w)));
            mn = fminf(mn, fminf(fminf(v.x, v.y), fminf(v.z, v.w)));
        }
        mx = wave_max(mx);
        mn = -wave_max(-mn);
        if ((t & 63) == 0) { red[t >> 6] = mx; red[8 + (t >> 6)] = mn; }
        __syncthreads();
        if (t == 0) {
            float M = red[0], N = red[8];
#pragma unroll
            for (int i = 1; i < 8; ++i) { M = fmaxf(M, red[i]); N = fminf(N, red[8 + i]); }
            ws_f[WS_XMX / 4 + c] = M;
            ws_f[WS_XMN / 4 + c] = N;
        }
    } else if (bid < 640) {
        int co = bid - 512;
        const float* w = cw + (size_t)co * 4608;
        float m = 0.f;
        for (int j = t; j < 4608; j += 512) m = fmaxf(m, fabsf(w[j]));
        m = wave_max(m);
        if ((t & 63) == 0) red[t >> 6] = m;
        __syncthreads();
        float mall = red[0];
#pragma unroll
        for (int i = 1; i < 8; ++i) mall = fmaxf(mall, red[i]);
        float sc = mall / 127.0f;
        if (t == 0) wsc[co] = sc;
        int ci = t >> 6, cq = (t >> 4) & 3, cb = t & 15;
#pragma unroll
        for (int tap = 0; tap < 9; ++tap) {
            float q = fminf(fmaxf(rintf(w[t * 9 + tap] / sc), -128.f), 127.f);
            wq[(((size_t)(tap * 8 + ci) * 4 + cq) * 128 + co) * 16 + cb] = (signed char)q;
        }
    } else {
        float wbn = gamma[t] / sqrtf(var[t] + 1e-5f);
        float bbn = beta[t] - mean[t] * wbn;
        float m = wave_max(fabsf(wbn));
        if ((t & 63) == 0) red[t >> 6] = m;
        __syncthreads();
        float mall = red[0];
#pragma unroll
        for (int i = 1; i < 8; ++i) mall = fmaxf(mall, red[i]);
        float ws_bn = mall / 127.0f;
        float s_in  = asf[0];
        float bn_sf = ws_bn * s_in;
        float wint  = fminf(fmaxf(rintf(wbn / ws_bn), -128.f), 127.f);
        float bint  = rintf(bbn / bn_sf);
        ws_f[WS_A1 / 4 + t] = wint * bn_sf / s_in;  // x1 = fmaf(x, A1, B1)
        ws_f[WS_B1 / 4 + t] = bint * bn_sf;
        if (t == 0) { ws_u[1] = 0u; ws_u[2] = 0u; }  // absmax(y) bits, barrier
    }
}

// ---- kernel 2: quantize x to int8 [ci][cq][w'][16] halo layout -------------
__global__ __launch_bounds__(256) void k_xquant(
    const float4* __restrict__ x4, float* __restrict__ ws_f,
    unsigned* __restrict__ x2u, unsigned* __restrict__ zrowu) {
    int bb = 31 - (blockIdx.x >> 5), h = blockIdx.x & 31;
    const float* A1 = ws_f + WS_A1 / 4;
    const float* B1 = ws_f + WS_B1 / 4;
    const float* XMX = ws_f + WS_XMX / 4;
    const float* XMN = ws_f + WS_XMN / 4;
    int t = threadIdx.x;

    // s_act from per-channel stats (exact: fma monotone in x, relu clamp >=0)
    __shared__ float sred[4];
    float cand = 0.f;
#pragma unroll
    for (int c0 = 0; c0 < 512; c0 += 256) {
        int c = c0 + t;
        float A = A1[c], B = B1[c];
        cand = fmaxf(cand, fmaxf(fmaf(XMX[c], A, B), fmaf(XMN[c], A, B)));
    }
    cand = wave_max(cand);
    if ((t & 63) == 0) sred[t >> 6] = cand;
    __syncthreads();
    float xm = fmaxf(fmaxf(sred[0], sred[1]), fmaxf(sred[2], sred[3]));
    float inv_sact = 127.0f / xm;
    if (blockIdx.x == 0 && t == 0) ws_f[3] = xm / 127.0f;  // s_act for k_conv

    size_t rowd = (size_t)(bb * 32 + h) * 4352;  // dwords per (b,h) row
    // zero halo columns w'=0,33
    {
        int p = t >> 3, side = (t >> 2) & 1, d = t & 3;
        x2u[rowd + (p * 34 + side * 33) * 4 + d] = 0u;
    }
    if (blockIdx.x < 17) {
        int idx = blockIdx.x * 256 + t;
        if (idx < 4352) zrowu[idx] = 0u;
    }

    __shared__ unsigned lds[512 * 9];  // [c][w4(8)] packed bytes, +1 pad

#pragma unroll
    for (int it = 0; it < 16; ++it) {
        int idx = it * 256 + t;
        int c = idx >> 3, f4 = idx & 7;
        float4 v = x4[((size_t)bb * 512 + c) * 256 + h * 8 + f4];
        float A = A1[c] * inv_sact, B = B1[c] * inv_sact;
        unsigned q0 = (unsigned)(int)fminf(rintf(fmaxf(fmaf(v.x, A, B), 0.f)), 127.f);
        unsigned q1 = (unsigned)(int)fminf(rintf(fmaxf(fmaf(v.y, A, B), 0.f)), 127.f);
        unsigned q2 = (unsigned)(int)fminf(rintf(fmaxf(fmaf(v.z, A, B), 0.f)), 127.f);
        unsigned q3 = (unsigned)(int)fminf(rintf(fmaxf(fmaf(v.w, A, B), 0.f)), 127.f);
        lds[c * 9 + f4] = q0 | (q1 << 8) | (q2 << 16) | (q3 << 24);
    }
    __syncthreads();

#pragma unroll
    for (int it = 0; it < 4; ++it) {
        int p = it * 8 + (t >> 5);   // 0..31 = ci*4+cq
        int s = (t >> 2) & 7;        // w4 group
        int k = t & 3;               // w = s*4+k, w' = w+1
        unsigned L[16];
#pragma unroll
        for (int j = 0; j < 16; ++j) L[j] = lds[(p * 16 + j) * 9 + s];
        uint4 o;
        unsigned* op = (unsigned*)&o;
#pragma unroll
        for (int d = 0; d < 4; ++d)
            op[d] = ((L[4 * d] >> (8 * k)) & 255u) |
                    (((L[4 * d + 1] >> (8 * k)) & 255u) << 8) |
                    (((L[4 * d + 2] >> (8 * k)) & 255u) << 16) |
                    (((L[4 * d + 3] >> (8 * k)) & 255u) << 24);
        *(uint4*)(x2u + rowd + (size_t)(p * 34 + s * 4 + 1 + k) * 4) = o;
    }
}

// ---- kernel 3: int8 3x3 conv + fused final requant ------------------------
// block = 4 waves = (rp in {0,1} row-pairs) x (kv in {0,1} K-halves), 64 co.
// grid 512 (XCD-swizzled), 2 blocks/CU => ALL blocks co-resident (confirmed
// empirically in R9: barrier resolved in-kernel), enabling the grid barrier
// for the global absmax(y) reduction. LDS 72KB: B stage (2 ci-slots of
// 36KB), reused as K-combine buffer (32KB) after the main loop.
__global__ __launch_bounds__(256, 2) void k_conv(
    const unsigned char* __restrict__ x2, const unsigned char* __restrict__ zrow,
    const signed char* __restrict__ wq,
    const float* __restrict__ wsc, const float* __restrict__ ws_f,
    unsigned* __restrict__ ws_u, float* __restrict__ y) {
    __shared__ char ldsb[73728];
    int t = threadIdx.x;
    int lane = t & 63, wv = t >> 6;
    int kv = wv & 1, rp = wv >> 1;
    int m = lane & 15, quad = lane >> 4;

    int bid = blockIdx.x;
    int tile = (bid & 7) * 64 + (bid >> 3);  // XCD swizzle, 64 tiles/XCD
    int ch = tile & 1;
    int rg = (tile >> 1) & 7;                // row-group of 4 rows
    int bb = tile >> 4;
    int co0 = ch * 64;
    int h0 = rg * 4 + rp * 2;                // this wave's first output row

    const unsigned char* xb = x2 + (size_t)bb * (32 * 17408);
    const v4i* rpt[4];
#pragma unroll
    for (int j = 0; j < 4; ++j) {
        int row = h0 - 1 + j;
        rpt[j] = (const v4i*)(((unsigned)row < 32u) ? (xb + (size_t)row * 17408) : zrow);
    }

    v4i acc[4][4];
#pragma unroll
    for (int i = 0; i < 4; ++i)
#pragma unroll
        for (int j = 0; j < 4; ++j) acc[i][j] = (v4i){0, 0, 0, 0};

    int abase = quad * 34 + m;

    for (int j = 0; j < 4; ++j) {
        // stage B for ci = j (kv0 slot) and ci = 4+j (kv1 slot): 72 chunks of
        // 1KB, 18 per wave. chunk c -> (kvs, tap, cq).
#pragma unroll
        for (int i = 0; i < 18; ++i) {
            int c = wv * 18 + i;
            int kvs = (c >= 36) ? 1 : 0;
            int rem = c - kvs * 36;
            int tap = rem >> 2, cq = rem & 3;
            int ci = kvs * 4 + j;
            const char* g = (const char*)wq +
                ((((size_t)(tap * 8 + ci) * 4 + cq) * 128 + co0) * 16) + lane * 16;
            char* s = ldsb + (((kvs * 9 + tap) * 4 + cq) << 10);
            stage16(g, s, lane);
        }
        __syncthreads();

        int ci = kv * 4 + j;
        const v4i* bbase = (const v4i*)ldsb + kv * 2304;  // 9*4*64 v4i per slot
#pragma unroll
        for (int kh = 0; kh < 3; ++kh)
#pragma unroll
            for (int kw = 0; kw < 3; ++kw) {
                int tap = kh * 3 + kw;
                v4i a[4];
#pragma unroll
                for (int mt = 0; mt < 4; ++mt)
                    a[mt] = rpt[kh + (mt >> 1)][ci * 136 + abase + kw + (mt & 1) * 16];
#pragma unroll
                for (int nt = 0; nt < 4; ++nt) {
                    v4i bf = bbase[(tap * 4 + quad) * 64 + nt * 16 + m];
#pragma unroll
                    for (int mt = 0; mt < 4; ++mt)
                        acc[mt][nt] = __builtin_amdgcn_mfma_i32_16x16x64_i8(a[mt], bf, acc[mt][nt], 0, 0, 0);
                }
            }
        __syncthreads();
    }

    // K-combine: kv=1 waves publish, kv=0 waves add (reuse stage LDS, 32KB)
    v4i* red = (v4i*)ldsb;
    if (kv == 1) {
#pragma unroll
        for (int mt = 0; mt < 4; ++mt)
#pragma unroll
            for (int nt = 0; nt < 4; ++nt)
                red[((rp * 16 + mt * 4 + nt) << 6) + lane] = acc[mt][nt];
    }
    __syncthreads();

    float s_act = ws_f[3];
    if (kv == 0) {
        float mx = 0.f;
#pragma unroll
        for (int nt = 0; nt < 4; ++nt) {
            float sf = s_act * wsc[co0 + nt * 16 + m];
#pragma unroll
            for (int mt = 0; mt < 4; ++mt) {
                v4i p = red[((rp * 16 + mt * 4 + nt) << 6) + lane];
                acc[mt][nt].x += p.x; acc[mt][nt].y += p.y;
                acc[mt][nt].z += p.z; acc[mt][nt].w += p.w;
                mx = fmaxf(mx, fmaxf(
                    fmaxf(fabsf((float)acc[mt][nt].x * sf), fabsf((float)acc[mt][nt].y * sf)),
                    fmaxf(fabsf((float)acc[mt][nt].z * sf), fabsf((float)acc[mt][nt].w * sf))));
            }
        }
        mx = wave_max(mx);
        if (lane == 0) atomicMax(ws_u + 1, __float_as_uint(mx));
    }

    // ---- grid barrier. The ACQ_REL add is ordered after this block's
    // atomicMax (the preceding __syncthreads drains vmcnt(0)). The POLL is a
    // RELAXED SYSTEM-scope load: sc0+sc1 bypass L1/L2 and read the memory-side
    // coherence point directly -> always sees the cross-XCD update, and emits
    // NO cache invalidation (R9's ACQUIRE/AGENT poll invalidated the shared
    // per-XCD L2 every iteration, thrashing still-running blocks). Bounded
    // spin guarantees termination (would fail verification, not hang).
    __syncthreads();
    if (t == 0) {
        __hip_atomic_fetch_add(ws_u + 2, 1u, __ATOMIC_ACQ_REL, __HIP_MEMORY_SCOPE_AGENT);
        int guard = 0;
        while (__hip_atomic_load(ws_u + 2, __ATOMIC_RELAXED, __HIP_MEMORY_SCOPE_SYSTEM) < 512u
               && ++guard < (1 << 20))
            __builtin_amdgcn_s_sleep(8);
    }
    __syncthreads();

    if (kv == 0) {
        // epilogue: requant in-register, write y ONCE.
        // C layout col(lane&15)=co, row(quad*4+reg)=w
        // s_out read with a cache-bypassing system load (RMWs executed at the
        // coherence point; all adds release-ordered before count==512).
        float s_out = __uint_as_float(
            __hip_atomic_load(ws_u + 1, __ATOMIC_RELAXED, __HIP_MEMORY_SCOPE_SYSTEM)) / 127.0f;
#pragma unroll
        for (int nt = 0; nt < 4; ++nt) {
            int co = co0 + nt * 16 + m;
            float sf = s_act * wsc[co];
#pragma unroll
            for (int mt = 0; mt < 4; ++mt) {
                int row = h0 + (mt >> 1);
                float* yb = y + ((size_t)(bb * 128 + co)) * 1024 + row * 32 + (mt & 1) * 16;
                float4 vv;
                vv.x = (float)acc[mt][nt][0] * sf;
                vv.y = (float)acc[mt][nt][1] * sf;
                vv.z = (float)acc[mt][nt][2] * sf;
                vv.w = (float)acc[mt][nt][3] * sf;
                vv.x = fminf(fmaxf(rintf(vv.x / s_out), -128.f), 127.f) * s_out;
                vv.y = fminf(fmaxf(rintf(vv.y / s_out), -128.f), 127.f) * s_out;
                vv.z = fminf(fmaxf(rintf(vv.z / s_out), -128.f), 127.f) * s_out;
                vv.w = fminf(fmaxf(rintf(vv.w / s_out), -128.f), 127.f) * s_out;
                *(float4*)(yb + quad * 4) = vv;
            }
        }
        if (blockIdx.x == 0 && t == 0) y[4194304] = s_out;
    }
}

extern "C" void kernel_launch(void* const* d_in, const int* in_sizes, int n_in,
                              void* d_out, int out_size, void* d_ws, size_t ws_size,
                              hipStream_t stream) {
    const float* x     = (const float*)d_in[0];
    const float* asf   = (const float*)d_in[1];
    const float* gamma = (const float*)d_in[2];
    const float* beta  = (const float*)d_in[3];
    const float* mean  = (const float*)d_in[4];
    const float* var   = (const float*)d_in[5];
    const float* cw    = (const float*)d_in[6];

    float*    ws_f = (float*)d_ws;
    unsigned* ws_u = (unsigned*)d_ws;
    signed char*   wq   = (signed char*)d_ws + WS_WQ;
    unsigned char* x2   = (unsigned char*)d_ws + WS_X2;
    unsigned char* zrow = (unsigned char*)d_ws + WS_ZROW;
    float* y = (float*)d_out;

    k_prep<<<641, 512, 0, stream>>>(gamma, beta, mean, var, asf, cw,
                                    (const float4*)x, ws_f, ws_u,
                                    ws_f + WS_WSC / 4, wq);
    k_xquant<<<1024, 256, 0, stream>>>((const float4*)x, ws_f,
                                       (unsigned*)x2, (unsigned*)zrow);
    k_conv<<<512, 256, 0, stream>>>(x2, zrow, wq, ws_f + WS_WSC / 4,
                                    ws_f, ws_u, y);
}

// Round 3
// 167.220 us; speedup vs baseline: 1.5539x; 1.1605x over previous
//
#include <hip/hip_runtime.h>

// ---------------------------------------------------------------------------
// Q_DenseLayer: BN-fold int8 affine -> ReLU -> per-tensor 8b quant ->
// int8 3x3 conv (MFMA i32_16x16x64_i8) -> per-tensor 8b requant.
// Shapes: x[32,512,32,32] f32, W[128,512,3,3] f32, out y[32,128,32,32] + s_out.
//
// R11: abandon the grid-barrier fusion (R9/R10: barrier region cost ~48us --
// 512 pollers on one coherence-point cacheline queue up and delay the counter
// adds; the y round-trip it saves is only ~7us). Back to split k_conv +
// k_yquant (R8 = 159.9us), and restructure k_conv for occupancy:
//   - NO K-split across waves (no K-combine LDS round-trip / extra syncs).
//   - block = 2 rows x 64 co, 4 waves = (row, co-half), wave = 1 row x 32 co.
//     acc = 4 v4i (16 regs, was 64).
//   - K-loop: 8 iters x one 64-ch ci-group; stage 36KB B per iter,
//     single-buffered -> LDS 36KB => 4 blocks/CU (was 2), 4 waves/SIMD.
//   - grid 1024 XCD-swizzled; __launch_bounds__(256,4) caps VGPR at 128.
// Layouts unchanged: x2 [b][h][ci8][cq4][w'34][16B], wq [tap][ci][cq4][co128][16B].
// Fixed ~95us harness work (ws poison + d_in restore) outside our control.
// ---------------------------------------------------------------------------

typedef int v4i __attribute__((ext_vector_type(4)));

// workspace byte offsets
#define WS_A1    64        // 512 f: A1_c = w_int*bn_sf/s_in
#define WS_B1    2112      // 512 f: B1_c = b_int*bn_sf
#define WS_WSC   4160      // 128 f
#define WS_XMX   4672      // 512 f: per-channel max(x)
#define WS_XMN   6720      // 512 f: per-channel min(x)
#define WS_WQ    8768      // 589824 i8: [tap][ci][cq][co128][16]
#define WS_X2    598592    // 17825792 u8: [b][h][ci][cq][w'34][16]
#define WS_ZROW  18424384  // 17408 u8 zero row
// ws_f[3] = s_act (k_xquant blk0), ws_u[1] = absmax(y) bits

__device__ __forceinline__ float wave_max(float m) {
#pragma unroll
    for (int off = 32; off; off >>= 1) m = fmaxf(m, __shfl_xor(m, off));
    return m;
}

// async global->LDS, 16B per lane: per-lane gsrc, wave-uniform LDS base
__device__ __forceinline__ void stage16(const char* g, char* s, int lane) {
#if defined(__has_builtin) && __has_builtin(__builtin_amdgcn_global_load_lds)
    __builtin_amdgcn_global_load_lds(
        (const __attribute__((address_space(1))) void*)g,
        (__attribute__((address_space(3))) void*)s, 16, 0, 0);
#else
    *(v4i*)(s + lane * 16) = *(const v4i*)g;
#endif
}

// ---- kernel 1: fused prep ---------------------------------------------------
// blocks 0..511:   per-channel x max/min (block c owns channel c)
// blocks 512..639: conv-weight quant (co = bid-512)
// block 640:       BN fold -> A1/B1, zero y-absmax
__global__ __launch_bounds__(512) void k_prep(
    const float* __restrict__ gamma, const float* __restrict__ beta,
    const float* __restrict__ mean,  const float* __restrict__ var,
    const float* __restrict__ asf,   const float* __restrict__ cw,
    const float4* __restrict__ x4,
    float* ws_f, unsigned* ws_u, float* __restrict__ wsc,
    signed char* __restrict__ wq) {
    int t = threadIdx.x;
    int bid = blockIdx.x;
    __shared__ float red[16];
    if (bid < 512) {
        int c = bid;
        float mx = -3.4e38f, mn = 3.4e38f;
#pragma unroll
        for (int r = 0; r < 16; ++r) {
            int bbb = r * 2 + (t >> 8);
            float4 v = x4[((size_t)(bbb * 512 + c)) * 256 + (t & 255)];
            mx = fmaxf(mx, fmaxf(fmaxf(v.x, v.y), fmaxf(v.z, v.w)));
            mn = fminf(mn, fminf(fminf(v.x, v.y), fminf(v.z, v.w)));
        }
        mx = wave_max(mx);
        mn = -wave_max(-mn);
        if ((t & 63) == 0) { red[t >> 6] = mx; red[8 + (t >> 6)] = mn; }
        __syncthreads();
        if (t == 0) {
            float M = red[0], N = red[8];
#pragma unroll
            for (int i = 1; i < 8; ++i) { M = fmaxf(M, red[i]); N = fminf(N, red[8 + i]); }
            ws_f[WS_XMX / 4 + c] = M;
            ws_f[WS_XMN / 4 + c] = N;
        }
    } else if (bid < 640) {
        int co = bid - 512;
        const float* w = cw + (size_t)co * 4608;
        float m = 0.f;
        for (int j = t; j < 4608; j += 512) m = fmaxf(m, fabsf(w[j]));
        m = wave_max(m);
        if ((t & 63) == 0) red[t >> 6] = m;
        __syncthreads();
        float mall = red[0];
#pragma unroll
        for (int i = 1; i < 8; ++i) mall = fmaxf(mall, red[i]);
        float sc = mall / 127.0f;
        if (t == 0) wsc[co] = sc;
        int ci = t >> 6, cq = (t >> 4) & 3, cb = t & 15;
#pragma unroll
        for (int tap = 0; tap < 9; ++tap) {
            float q = fminf(fmaxf(rintf(w[t * 9 + tap] / sc), -128.f), 127.f);
            wq[(((size_t)(tap * 8 + ci) * 4 + cq) * 128 + co) * 16 + cb] = (signed char)q;
        }
    } else {
        float wbn = gamma[t] / sqrtf(var[t] + 1e-5f);
        float bbn = beta[t] - mean[t] * wbn;
        float m = wave_max(fabsf(wbn));
        if ((t & 63) == 0) red[t >> 6] = m;
        __syncthreads();
        float mall = red[0];
#pragma unroll
        for (int i = 1; i < 8; ++i) mall = fmaxf(mall, red[i]);
        float ws_bn = mall / 127.0f;
        float s_in  = asf[0];
        float bn_sf = ws_bn * s_in;
        float wint  = fminf(fmaxf(rintf(wbn / ws_bn), -128.f), 127.f);
        float bint  = rintf(bbn / bn_sf);
        ws_f[WS_A1 / 4 + t] = wint * bn_sf / s_in;  // x1 = fmaf(x, A1, B1)
        ws_f[WS_B1 / 4 + t] = bint * bn_sf;
        if (t == 0) ws_u[1] = 0u;  // absmax(y) bits
    }
}

// ---- kernel 2: quantize x to int8 [ci][cq][w'][16] halo layout -------------
__global__ __launch_bounds__(256) void k_xquant(
    const float4* __restrict__ x4, float* __restrict__ ws_f,
    unsigned* __restrict__ x2u, unsigned* __restrict__ zrowu) {
    int bb = 31 - (blockIdx.x >> 5), h = blockIdx.x & 31;
    const float* A1 = ws_f + WS_A1 / 4;
    const float* B1 = ws_f + WS_B1 / 4;
    const float* XMX = ws_f + WS_XMX / 4;
    const float* XMN = ws_f + WS_XMN / 4;
    int t = threadIdx.x;

    // s_act from per-channel stats (exact: fma monotone in x, relu clamp >=0)
    __shared__ float sred[4];
    float cand = 0.f;
#pragma unroll
    for (int c0 = 0; c0 < 512; c0 += 256) {
        int c = c0 + t;
        float A = A1[c], B = B1[c];
        cand = fmaxf(cand, fmaxf(fmaf(XMX[c], A, B), fmaf(XMN[c], A, B)));
    }
    cand = wave_max(cand);
    if ((t & 63) == 0) sred[t >> 6] = cand;
    __syncthreads();
    float xm = fmaxf(fmaxf(sred[0], sred[1]), fmaxf(sred[2], sred[3]));
    float inv_sact = 127.0f / xm;
    if (blockIdx.x == 0 && t == 0) ws_f[3] = xm / 127.0f;  // s_act for k_conv

    size_t rowd = (size_t)(bb * 32 + h) * 4352;  // dwords per (b,h) row
    // zero halo columns w'=0,33
    {
        int p = t >> 3, side = (t >> 2) & 1, d = t & 3;
        x2u[rowd + (p * 34 + side * 33) * 4 + d] = 0u;
    }
    if (blockIdx.x < 17) {
        int idx = blockIdx.x * 256 + t;
        if (idx < 4352) zrowu[idx] = 0u;
    }

    __shared__ unsigned lds[512 * 9];  // [c][w4(8)] packed bytes, +1 pad

#pragma unroll
    for (int it = 0; it < 16; ++it) {
        int idx = it * 256 + t;
        int c = idx >> 3, f4 = idx & 7;
        float4 v = x4[((size_t)bb * 512 + c) * 256 + h * 8 + f4];
        float A = A1[c] * inv_sact, B = B1[c] * inv_sact;
        unsigned q0 = (unsigned)(int)fminf(rintf(fmaxf(fmaf(v.x, A, B), 0.f)), 127.f);
        unsigned q1 = (unsigned)(int)fminf(rintf(fmaxf(fmaf(v.y, A, B), 0.f)), 127.f);
        unsigned q2 = (unsigned)(int)fminf(rintf(fmaxf(fmaf(v.z, A, B), 0.f)), 127.f);
        unsigned q3 = (unsigned)(int)fminf(rintf(fmaxf(fmaf(v.w, A, B), 0.f)), 127.f);
        lds[c * 9 + f4] = q0 | (q1 << 8) | (q2 << 16) | (q3 << 24);
    }
    __syncthreads();

#pragma unroll
    for (int it = 0; it < 4; ++it) {
        int p = it * 8 + (t >> 5);   // 0..31 = ci*4+cq
        int s = (t >> 2) & 7;        // w4 group
        int k = t & 3;               // w = s*4+k, w' = w+1
        unsigned L[16];
#pragma unroll
        for (int j = 0; j < 16; ++j) L[j] = lds[(p * 16 + j) * 9 + s];
        uint4 o;
        unsigned* op = (unsigned*)&o;
#pragma unroll
        for (int d = 0; d < 4; ++d)
            op[d] = ((L[4 * d] >> (8 * k)) & 255u) |
                    (((L[4 * d + 1] >> (8 * k)) & 255u) << 8) |
                    (((L[4 * d + 2] >> (8 * k)) & 255u) << 16) |
                    (((L[4 * d + 3] >> (8 * k)) & 255u) << 24);
        *(uint4*)(x2u + rowd + (size_t)(p * 34 + s * 4 + 1 + k) * 4) = o;
    }
}

// ---- kernel 3: int8 3x3 conv, no K-split, 4 blocks/CU ----------------------
// block = 2 output rows x 64 co; 4 waves = (wr row, nh co-half);
// wave = 1 row x 32 co x 32 w, acc[2][2] (mt = w-half, nt = co-16-group).
// K-loop: 8 iters over 64-channel ci-groups; per iter stage 36KB of B
// ([tap9][cq4][co64][16B]) via global_load_lds, consumed by all 4 waves.
// LDS 36KB -> 4 blocks/CU (16 waves/CU, 4/SIMD) for latency hiding; the
// per-iter barrier drains overlap across the 4 independent blocks.
__global__ __launch_bounds__(256, 4) void k_conv(
    const unsigned char* __restrict__ x2, const unsigned char* __restrict__ zrow,
    const signed char* __restrict__ wq,
    const float* __restrict__ wsc, const float* __restrict__ ws_f,
    unsigned* __restrict__ amaxy, float* __restrict__ y) {
    __shared__ char ldsb[36864];
    int t = threadIdx.x;
    int lane = t & 63, wv = t >> 6;
    int nh = wv & 1, wr = wv >> 1;   // co-half, row-within-block
    int m = lane & 15, quad = lane >> 4;

    int bid = blockIdx.x;
    int tile = (bid & 7) * 128 + (bid >> 3);  // XCD swizzle, 128 tiles/XCD
    int ch = tile & 1;                        // co 0..63 / 64..127
    int rg = (tile >> 1) & 15;                // row-pair group
    int bb = tile >> 5;
    int co0 = ch * 64;
    int h0 = rg * 2;                          // block's first output row

    const unsigned char* xb = x2 + (size_t)bb * (32 * 17408);
    const v4i* rpt[4];
#pragma unroll
    for (int j = 0; j < 4; ++j) {
        int row = h0 - 1 + j;
        rpt[j] = (const v4i*)(((unsigned)row < 32u) ? (xb + (size_t)row * 17408) : zrow);
    }

    v4i acc[2][2];
#pragma unroll
    for (int i = 0; i < 2; ++i)
#pragma unroll
        for (int j = 0; j < 2; ++j) acc[i][j] = (v4i){0, 0, 0, 0};

    int abase = quad * 34 + m;
    const v4i* bv = (const v4i*)ldsb;

    for (int ci = 0; ci < 8; ++ci) {
        __syncthreads();  // all waves done reading previous B tile
        // stage B for this ci-group: 36 chunks of 1KB (tap9 x cq4), 9/wave
#pragma unroll
        for (int i = 0; i < 9; ++i) {
            int c = wv * 9 + i;
            int tap = c >> 2, cq = c & 3;
            const char* g = (const char*)wq +
                ((((size_t)(tap * 8 + ci) * 4 + cq) * 128 + co0) * 16) + lane * 16;
            stage16(g, ldsb + (c << 10), lane);
        }
        __syncthreads();  // staged data visible (vmcnt drained per-wave)

#pragma unroll
        for (int kh = 0; kh < 3; ++kh)
#pragma unroll
            for (int kw = 0; kw < 3; ++kw) {
                int tap = kh * 3 + kw;
                v4i a0 = rpt[wr + kh][ci * 136 + abase + kw];
                v4i a1 = rpt[wr + kh][ci * 136 + abase + kw + 16];
#pragma unroll
                for (int nt = 0; nt < 2; ++nt) {
                    v4i bf = bv[(tap * 4 + quad) * 64 + nh * 32 + nt * 16 + m];
                    acc[0][nt] = __builtin_amdgcn_mfma_i32_16x16x64_i8(a0, bf, acc[0][nt], 0, 0, 0);
                    acc[1][nt] = __builtin_amdgcn_mfma_i32_16x16x64_i8(a1, bf, acc[1][nt], 0, 0, 0);
                }
            }
    }

    // epilogue: C layout col(lane&15)=co, row(quad*4+reg)=w; y unquantized,
    // track block absmax -> one device atomicMax per block.
    float s_act = ws_f[3];
    float mx = 0.f;
    int row = h0 + wr;
#pragma unroll
    for (int nt = 0; nt < 2; ++nt) {
        int co = co0 + nh * 32 + nt * 16 + m;
        float sf = s_act * wsc[co];
        float* yb = y + ((size_t)(bb * 128 + co)) * 1024 + row * 32;
#pragma unroll
        for (int mt = 0; mt < 2; ++mt) {
            float4 vv;
            vv.x = (float)acc[mt][nt][0] * sf;
            vv.y = (float)acc[mt][nt][1] * sf;
            vv.z = (float)acc[mt][nt][2] * sf;
            vv.w = (float)acc[mt][nt][3] * sf;
            *(float4*)(yb + mt * 16 + quad * 4) = vv;
            mx = fmaxf(mx, fmaxf(fmaxf(fabsf(vv.x), fabsf(vv.y)),
                                 fmaxf(fabsf(vv.z), fabsf(vv.w))));
        }
    }
    mx = wave_max(mx);
    __syncthreads();  // all B reads done before reusing ldsb
    if (lane == 0) ((float*)ldsb)[wv] = mx;
    __syncthreads();
    if (t == 0) {
        float* r = (float*)ldsb;
        float M = fmaxf(fmaxf(r[0], r[1]), fmaxf(r[2], r[3]));
        atomicMax(amaxy, __float_as_uint(M));
    }
}

// ---- kernel 4: final requant in place + write s_out -----------------------
__global__ __launch_bounds__(256) void k_yquant(float* __restrict__ yout,
                                                const unsigned* __restrict__ ws_u) {
    float s_out = __uint_as_float(ws_u[1]) / 127.0f;
    float4* y4 = (float4*)yout;
    int stride = gridDim.x * blockDim.x;
    for (int i = blockIdx.x * blockDim.x + threadIdx.x; i < 1048576; i += stride) {
        float4 v = y4[i];
        v.x = fminf(fmaxf(rintf(v.x / s_out), -128.f), 127.f) * s_out;
        v.y = fminf(fmaxf(rintf(v.y / s_out), -128.f), 127.f) * s_out;
        v.z = fminf(fmaxf(rintf(v.z / s_out), -128.f), 127.f) * s_out;
        v.w = fminf(fmaxf(rintf(v.w / s_out), -128.f), 127.f) * s_out;
        y4[i] = v;
    }
    if (blockIdx.x == 0 && threadIdx.x == 0) yout[4194304] = s_out;
}

extern "C" void kernel_launch(void* const* d_in, const int* in_sizes, int n_in,
                              void* d_out, int out_size, void* d_ws, size_t ws_size,
                              hipStream_t stream) {
    const float* x     = (const float*)d_in[0];
    const float* asf   = (const float*)d_in[1];
    const float* gamma = (const float*)d_in[2];
    const float* beta  = (const float*)d_in[3];
    const float* mean  = (const float*)d_in[4];
    const float* var   = (const float*)d_in[5];
    const float* cw    = (const float*)d_in[6];

    float*    ws_f = (float*)d_ws;
    unsigned* ws_u = (unsigned*)d_ws;
    signed char*   wq   = (signed char*)d_ws + WS_WQ;
    unsigned char* x2   = (unsigned char*)d_ws + WS_X2;
    unsigned char* zrow = (unsigned char*)d_ws + WS_ZROW;
    float* y = (float*)d_out;

    k_prep<<<641, 512, 0, stream>>>(gamma, beta, mean, var, asf, cw,
                                    (const float4*)x, ws_f, ws_u,
                                    ws_f + WS_WSC / 4, wq);
    k_xquant<<<1024, 256, 0, stream>>>((const float4*)x, ws_f,
                                       (unsigned*)x2, (unsigned*)zrow);
    k_conv<<<1024, 256, 0, stream>>>(x2, zrow, wq, ws_f + WS_WSC / 4,
                                     ws_f, ws_u + 1, y);
    k_yquant<<<1024, 256, 0, stream>>>(y, ws_u);
}

// Round 4
// 159.220 us; speedup vs baseline: 1.6320x; 1.0502x over previous
//
#include <hip/hip_runtime.h>

// ---------------------------------------------------------------------------
// Q_DenseLayer: BN-fold int8 affine -> ReLU -> per-tensor 8b quant ->
// int8 3x3 conv (MFMA i32_16x16x64_i8) -> per-tensor 8b requant.
// Shapes: x[32,512,32,32] f32, W[128,512,3,3] f32, out y[32,128,32,32] + s_out.
//
// R12: k_conv rebuilt around pipe-budget arithmetic (floors per CU: MFMA
// 1.18M/256*5cyc = 9.6us, TA = A-loads + B-stage ~11us, LDS ~8us):
//   - wave = 2 rows x 16 w x 64 co -> per tap 2 A-frags feed 8 MFMAs:
//     A-reuse 4 (R11 had 2 -> 590MB A traffic, ~15us TA floor; now 294MB).
//   - block = 4 waves (row-pair x w-half) = 4 rows x 64 co, grid 512
//     (XCD-swizzled), no K-split (no K-combine round-trip).
//   - B DOUBLE-BUFFERED (2x36KB LDS, 2 blocks/CU, 8 waves/CU): stage(next)
//     issued at top of iter, compute(cur) runs ~72 MFMA/wave, single
//     __syncthreads at END drains vmcnt AFTER compute -> L2 stage latency
//     off the critical path (T3 2-phase minimum recipe). 1 barrier/K-step.
// R11 kept: split k_conv/k_yquant (grid-barrier fusion dead: R9/R10 showed
// coherence-point polling costs ~48us vs ~7us saved).
// Layouts: x2 [b][h][ci8][cq4][w'34][16B], wq [tap][ci][cq4][co128][16B].
// Fixed ~95us harness work (ws poison + d_in restore) outside our control.
// ---------------------------------------------------------------------------

typedef int v4i __attribute__((ext_vector_type(4)));

// workspace byte offsets
#define WS_A1    64        // 512 f: A1_c = w_int*bn_sf/s_in
#define WS_B1    2112      // 512 f: B1_c = b_int*bn_sf
#define WS_WSC   4160      // 128 f
#define WS_XMX   4672      // 512 f: per-channel max(x)
#define WS_XMN   6720      // 512 f: per-channel min(x)
#define WS_WQ    8768      // 589824 i8: [tap][ci][cq][co128][16]
#define WS_X2    598592    // 17825792 u8: [b][h][ci][cq][w'34][16]
#define WS_ZROW  18424384  // 17408 u8 zero row
// ws_f[3] = s_act (k_xquant blk0), ws_u[1] = absmax(y) bits

__device__ __forceinline__ float wave_max(float m) {
#pragma unroll
    for (int off = 32; off; off >>= 1) m = fmaxf(m, __shfl_xor(m, off));
    return m;
}

// async global->LDS, 16B per lane: per-lane gsrc, wave-uniform LDS base
__device__ __forceinline__ void stage16(const char* g, char* s, int lane) {
#if defined(__has_builtin) && __has_builtin(__builtin_amdgcn_global_load_lds)
    __builtin_amdgcn_global_load_lds(
        (const __attribute__((address_space(1))) void*)g,
        (__attribute__((address_space(3))) void*)s, 16, 0, 0);
#else
    *(v4i*)(s + lane * 16) = *(const v4i*)g;
#endif
}

// ---- kernel 1: fused prep ---------------------------------------------------
// blocks 0..511:   per-channel x max/min (block c owns channel c)
// blocks 512..639: conv-weight quant (co = bid-512)
// block 640:       BN fold -> A1/B1, zero y-absmax
__global__ __launch_bounds__(512) void k_prep(
    const float* __restrict__ gamma, const float* __restrict__ beta,
    const float* __restrict__ mean,  const float* __restrict__ var,
    const float* __restrict__ asf,   const float* __restrict__ cw,
    const float4* __restrict__ x4,
    float* ws_f, unsigned* ws_u, float* __restrict__ wsc,
    signed char* __restrict__ wq) {
    int t = threadIdx.x;
    int bid = blockIdx.x;
    __shared__ float red[16];
    if (bid < 512) {
        int c = bid;
        float mx = -3.4e38f, mn = 3.4e38f;
#pragma unroll
        for (int r = 0; r < 16; ++r) {
            int bbb = r * 2 + (t >> 8);
            float4 v = x4[((size_t)(bbb * 512 + c)) * 256 + (t & 255)];
            mx = fmaxf(mx, fmaxf(fmaxf(v.x, v.y), fmaxf(v.z, v.w)));
            mn = fminf(mn, fminf(fminf(v.x, v.y), fminf(v.z, v.w)));
        }
        mx = wave_max(mx);
        mn = -wave_max(-mn);
        if ((t & 63) == 0) { red[t >> 6] = mx; red[8 + (t >> 6)] = mn; }
        __syncthreads();
        if (t == 0) {
            float M = red[0], N = red[8];
#pragma unroll
            for (int i = 1; i < 8; ++i) { M = fmaxf(M, red[i]); N = fminf(N, red[8 + i]); }
            ws_f[WS_XMX / 4 + c] = M;
            ws_f[WS_XMN / 4 + c] = N;
        }
    } else if (bid < 640) {
        int co = bid - 512;
        const float* w = cw + (size_t)co * 4608;
        float m = 0.f;
        for (int j = t; j < 4608; j += 512) m = fmaxf(m, fabsf(w[j]));
        m = wave_max(m);
        if ((t & 63) == 0) red[t >> 6] = m;
        __syncthreads();
        float mall = red[0];
#pragma unroll
        for (int i = 1; i < 8; ++i) mall = fmaxf(mall, red[i]);
        float sc = mall / 127.0f;
        if (t == 0) wsc[co] = sc;
        int ci = t >> 6, cq = (t >> 4) & 3, cb = t & 15;
#pragma unroll
        for (int tap = 0; tap < 9; ++tap) {
            float q = fminf(fmaxf(rintf(w[t * 9 + tap] / sc), -128.f), 127.f);
            wq[(((size_t)(tap * 8 + ci) * 4 + cq) * 128 + co) * 16 + cb] = (signed char)q;
        }
    } else {
        float wbn = gamma[t] / sqrtf(var[t] + 1e-5f);
        float bbn = beta[t] - mean[t] * wbn;
        float m = wave_max(fabsf(wbn));
        if ((t & 63) == 0) red[t >> 6] = m;
        __syncthreads();
        float mall = red[0];
#pragma unroll
        for (int i = 1; i < 8; ++i) mall = fmaxf(mall, red[i]);
        float ws_bn = mall / 127.0f;
        float s_in  = asf[0];
        float bn_sf = ws_bn * s_in;
        float wint  = fminf(fmaxf(rintf(wbn / ws_bn), -128.f), 127.f);
        float bint  = rintf(bbn / bn_sf);
        ws_f[WS_A1 / 4 + t] = wint * bn_sf / s_in;  // x1 = fmaf(x, A1, B1)
        ws_f[WS_B1 / 4 + t] = bint * bn_sf;
        if (t == 0) ws_u[1] = 0u;  // absmax(y) bits
    }
}

// ---- kernel 2: quantize x to int8 [ci][cq][w'][16] halo layout -------------
__global__ __launch_bounds__(256) void k_xquant(
    const float4* __restrict__ x4, float* __restrict__ ws_f,
    unsigned* __restrict__ x2u, unsigned* __restrict__ zrowu) {
    int bb = 31 - (blockIdx.x >> 5), h = blockIdx.x & 31;
    const float* A1 = ws_f + WS_A1 / 4;
    const float* B1 = ws_f + WS_B1 / 4;
    const float* XMX = ws_f + WS_XMX / 4;
    const float* XMN = ws_f + WS_XMN / 4;
    int t = threadIdx.x;

    // s_act from per-channel stats (exact: fma monotone in x, relu clamp >=0)
    __shared__ float sred[4];
    float cand = 0.f;
#pragma unroll
    for (int c0 = 0; c0 < 512; c0 += 256) {
        int c = c0 + t;
        float A = A1[c], B = B1[c];
        cand = fmaxf(cand, fmaxf(fmaf(XMX[c], A, B), fmaf(XMN[c], A, B)));
    }
    cand = wave_max(cand);
    if ((t & 63) == 0) sred[t >> 6] = cand;
    __syncthreads();
    float xm = fmaxf(fmaxf(sred[0], sred[1]), fmaxf(sred[2], sred[3]));
    float inv_sact = 127.0f / xm;
    if (blockIdx.x == 0 && t == 0) ws_f[3] = xm / 127.0f;  // s_act for k_conv

    size_t rowd = (size_t)(bb * 32 + h) * 4352;  // dwords per (b,h) row
    // zero halo columns w'=0,33
    {
        int p = t >> 3, side = (t >> 2) & 1, d = t & 3;
        x2u[rowd + (p * 34 + side * 33) * 4 + d] = 0u;
    }
    if (blockIdx.x < 17) {
        int idx = blockIdx.x * 256 + t;
        if (idx < 4352) zrowu[idx] = 0u;
    }

    __shared__ unsigned lds[512 * 9];  // [c][w4(8)] packed bytes, +1 pad

#pragma unroll
    for (int it = 0; it < 16; ++it) {
        int idx = it * 256 + t;
        int c = idx >> 3, f4 = idx & 7;
        float4 v = x4[((size_t)bb * 512 + c) * 256 + h * 8 + f4];
        float A = A1[c] * inv_sact, B = B1[c] * inv_sact;
        unsigned q0 = (unsigned)(int)fminf(rintf(fmaxf(fmaf(v.x, A, B), 0.f)), 127.f);
        unsigned q1 = (unsigned)(int)fminf(rintf(fmaxf(fmaf(v.y, A, B), 0.f)), 127.f);
        unsigned q2 = (unsigned)(int)fminf(rintf(fmaxf(fmaf(v.z, A, B), 0.f)), 127.f);
        unsigned q3 = (unsigned)(int)fminf(rintf(fmaxf(fmaf(v.w, A, B), 0.f)), 127.f);
        lds[c * 9 + f4] = q0 | (q1 << 8) | (q2 << 16) | (q3 << 24);
    }
    __syncthreads();

#pragma unroll
    for (int it = 0; it < 4; ++it) {
        int p = it * 8 + (t >> 5);   // 0..31 = ci*4+cq
        int s = (t >> 2) & 7;        // w4 group
        int k = t & 3;               // w = s*4+k, w' = w+1
        unsigned L[16];
#pragma unroll
        for (int j = 0; j < 16; ++j) L[j] = lds[(p * 16 + j) * 9 + s];
        uint4 o;
        unsigned* op = (unsigned*)&o;
#pragma unroll
        for (int d = 0; d < 4; ++d)
            op[d] = ((L[4 * d] >> (8 * k)) & 255u) |
                    (((L[4 * d + 1] >> (8 * k)) & 255u) << 8) |
                    (((L[4 * d + 2] >> (8 * k)) & 255u) << 16) |
                    (((L[4 * d + 3] >> (8 * k)) & 255u) << 24);
        *(uint4*)(x2u + rowd + (size_t)(p * 34 + s * 4 + 1 + k) * 4) = o;
    }
}

// ---- kernel 3: int8 3x3 conv, double-buffered B, A-reuse 4 -----------------
// block = 4 rows x 64 co, 4 waves = (rp row-pair, wh w-half);
// wave = 2 rows x 16 w x 64 co, acc[2][4] (r = row, nt = co-16-group).
// K-loop: 8 iters over 64-ch ci-groups. Per iter: stage NEXT B tile (36KB,
// 9 global_load_lds/wave) at TOP, compute current from the other buffer
// (per tap: 2 A-frags -> 8 MFMAs; A-reuse 4), ONE __syncthreads at END
// (vmcnt drain lands after ~72 MFMA/wave of compute -> stage latency hidden).
// LDS 2x36KB=72KB -> 2 blocks/CU, 8 waves/CU.
__global__ __launch_bounds__(256, 2) void k_conv(
    const unsigned char* __restrict__ x2, const unsigned char* __restrict__ zrow,
    const signed char* __restrict__ wq,
    const float* __restrict__ wsc, const float* __restrict__ ws_f,
    unsigned* __restrict__ amaxy, float* __restrict__ y) {
    __shared__ char ldsb[73728];
    int t = threadIdx.x;
    int lane = t & 63, wv = t >> 6;
    int wh = wv & 1, rp = wv >> 1;   // w-half, row-pair
    int m = lane & 15, quad = lane >> 4;

    int bid = blockIdx.x;
    int tile = (bid & 7) * 64 + (bid >> 3);  // XCD swizzle, 64 tiles/XCD
    int ch = tile & 1;
    int rg = (tile >> 1) & 7;                // row-group of 4 rows
    int bb = tile >> 4;
    int co0 = ch * 64;
    int h0 = rg * 4 + rp * 2;                // this wave's first output row

    const unsigned char* xb = x2 + (size_t)bb * (32 * 17408);
    const v4i* rpt[4];
#pragma unroll
    for (int j = 0; j < 4; ++j) {
        int row = h0 - 1 + j;
        rpt[j] = (const v4i*)(((unsigned)row < 32u) ? (xb + (size_t)row * 17408) : zrow);
    }

    v4i acc[2][4];
#pragma unroll
    for (int i = 0; i < 2; ++i)
#pragma unroll
        for (int j = 0; j < 4; ++j) acc[i][j] = (v4i){0, 0, 0, 0};

    int abase = quad * 34 + m + wh * 16;  // [cq=quad][w'=m+wh*16] in v4i units

    // prologue: stage ci=0 into buffer 0 (36 x 1KB chunks, 9 per wave)
#pragma unroll
    for (int i = 0; i < 9; ++i) {
        int c = wv * 9 + i;
        int tap = c >> 2, cq = c & 3;
        const char* g = (const char*)wq +
            ((((size_t)(tap * 8 + 0) * 4 + cq) * 128 + co0) * 16) + lane * 16;
        stage16(g, ldsb + (c << 10), lane);
    }
    __syncthreads();

#pragma unroll
    for (int ci = 0; ci < 8; ++ci) {
        // stage NEXT ci-group into the other buffer (latency hides under MFMA)
        if (ci < 7) {
#pragma unroll
            for (int i = 0; i < 9; ++i) {
                int c = wv * 9 + i;
                int tap = c >> 2, cq = c & 3;
                const char* g = (const char*)wq +
                    ((((size_t)(tap * 8 + ci + 1) * 4 + cq) * 128 + co0) * 16) + lane * 16;
                stage16(g, ldsb + ((ci + 1) & 1) * 36864 + (c << 10), lane);
            }
        }
        const v4i* bv = (const v4i*)(ldsb + (ci & 1) * 36864);
#pragma unroll
        for (int kh = 0; kh < 3; ++kh)
#pragma unroll
            for (int kw = 0; kw < 3; ++kw) {
                int tap = kh * 3 + kw;
                v4i a0 = rpt[kh][ci * 136 + abase + kw];      // out row h0
                v4i a1 = rpt[kh + 1][ci * 136 + abase + kw];  // out row h0+1
#pragma unroll
                for (int nt = 0; nt < 4; ++nt) {
                    v4i bf = bv[(tap * 4 + quad) * 64 + nt * 16 + m];
                    acc[0][nt] = __builtin_amdgcn_mfma_i32_16x16x64_i8(a0, bf, acc[0][nt], 0, 0, 0);
                    acc[1][nt] = __builtin_amdgcn_mfma_i32_16x16x64_i8(a1, bf, acc[1][nt], 0, 0, 0);
                }
            }
        __syncthreads();  // all reads of cur done + next-buf stages drained
    }

    // epilogue: C layout col(lane&15)=co, row(quad*4+reg)=w-within-half.
    // y unquantized; track block absmax -> one atomicMax per block.
    float s_act = ws_f[3];
    float mx = 0.f;
#pragma unroll
    for (int nt = 0; nt < 4; ++nt) {
        int co = co0 + nt * 16 + m;
        float sf = s_act * wsc[co];
#pragma unroll
        for (int r = 0; r < 2; ++r) {
            int row = h0 + r;
            float* yb = y + ((size_t)(bb * 128 + co)) * 1024 + row * 32 + wh * 16;
            float4 vv;
            vv.x = (float)acc[r][nt][0] * sf;
            vv.y = (float)acc[r][nt][1] * sf;
            vv.z = (float)acc[r][nt][2] * sf;
            vv.w = (float)acc[r][nt][3] * sf;
            *(float4*)(yb + quad * 4) = vv;
            mx = fmaxf(mx, fmaxf(fmaxf(fabsf(vv.x), fabsf(vv.y)),
                                 fmaxf(fabsf(vv.z), fabsf(vv.w))));
        }
    }
    mx = wave_max(mx);
    if (lane == 0) ((float*)ldsb)[wv] = mx;   // loop ended with __syncthreads
    __syncthreads();
    if (t == 0) {
        float* r = (float*)ldsb;
        float M = fmaxf(fmaxf(r[0], r[1]), fmaxf(r[2], r[3]));
        atomicMax(amaxy, __float_as_uint(M));
    }
}

// ---- kernel 4: final requant in place + write s_out -----------------------
__global__ __launch_bounds__(256) void k_yquant(float* __restrict__ yout,
                                                const unsigned* __restrict__ ws_u) {
    float s_out = __uint_as_float(ws_u[1]) / 127.0f;
    float4* y4 = (float4*)yout;
    int stride = gridDim.x * blockDim.x;
    for (int i = blockIdx.x * blockDim.x + threadIdx.x; i < 1048576; i += stride) {
        float4 v = y4[i];
        v.x = fminf(fmaxf(rintf(v.x / s_out), -128.f), 127.f) * s_out;
        v.y = fminf(fmaxf(rintf(v.y / s_out), -128.f), 127.f) * s_out;
        v.z = fminf(fmaxf(rintf(v.z / s_out), -128.f), 127.f) * s_out;
        v.w = fminf(fmaxf(rintf(v.w / s_out), -128.f), 127.f) * s_out;
        y4[i] = v;
    }
    if (blockIdx.x == 0 && threadIdx.x == 0) yout[4194304] = s_out;
}

extern "C" void kernel_launch(void* const* d_in, const int* in_sizes, int n_in,
                              void* d_out, int out_size, void* d_ws, size_t ws_size,
                              hipStream_t stream) {
    const float* x     = (const float*)d_in[0];
    const float* asf   = (const float*)d_in[1];
    const float* gamma = (const float*)d_in[2];
    const float* beta  = (const float*)d_in[3];
    const float* mean  = (const float*)d_in[4];
    const float* var   = (const float*)d_in[5];
    const float* cw    = (const float*)d_in[6];

    float*    ws_f = (float*)d_ws;
    unsigned* ws_u = (unsigned*)d_ws;
    signed char*   wq   = (signed char*)d_ws + WS_WQ;
    unsigned char* x2   = (unsigned char*)d_ws + WS_X2;
    unsigned char* zrow = (unsigned char*)d_ws + WS_ZROW;
    float* y = (float*)d_out;

    k_prep<<<641, 512, 0, stream>>>(gamma, beta, mean, var, asf, cw,
                                    (const float4*)x, ws_f, ws_u,
                                    ws_f + WS_WSC / 4, wq);
    k_xquant<<<1024, 256, 0, stream>>>((const float4*)x, ws_f,
                                       (unsigned*)x2, (unsigned*)zrow);
    k_conv<<<512, 256, 0, stream>>>(x2, zrow, wq, ws_f + WS_WSC / 4,
                                    ws_f, ws_u + 1, y);
    k_yquant<<<1024, 256, 0, stream>>>(y, ws_u);
}

// Round 5
// 152.197 us; speedup vs baseline: 1.7073x; 1.0461x over previous
//
#include <hip/hip_runtime.h>

// ---------------------------------------------------------------------------
// Q_DenseLayer: BN-fold int8 affine -> ReLU -> per-tensor 8b quant ->
// int8 3x3 conv (MFMA i32_16x16x64_i8) -> per-tensor 8b requant.
// Shapes: x[32,512,32,32] f32, W[128,512,3,3] f32, out y[32,128,32,32] + s_out.
//
// R13: force per-wave ILP in k_conv. R12 measured ~33us; a sum-of-pipes model
// (MFMA 2940 + LDS 2300 + VMEM 2690 cyc/iter/CU ~= 26us + barriers) fits it
// exactly -> pipes serialize. R11's VGPR_Count=52 shows the compiler
// under-hoisted (left 200 regs unused, scheduled load->wait->MFMA chains).
// Fix: explicit register blocking -- hoist all 12 A-frags (A[4][3], 48 VGPR,
// kh-chain CSE: in-rows r-1..r+2 x 3 kw) at iter top, then per kh batch 12
// B ds_reads before a 24-MFMA cluster wrapped in s_setprio(1)/(0) (T5: 2
// blocks/CU barrier skew gives role diversity). ~160 VGPR under (256,2).
// R12 kept: dbuf B (2x36KB), 1 barrier/iter, wave = 2 rows x 16 w x 64 co
// (A-reuse 4), grid 512 XCD-swizzled, no K-split.
// Layouts: x2 [b][h][ci8][cq4][w'34][16B], wq [tap][ci][cq4][co128][16B].
// Fixed ~95us harness work (ws poison + d_in restore) outside our control.
// ---------------------------------------------------------------------------

typedef int v4i __attribute__((ext_vector_type(4)));

// workspace byte offsets
#define WS_A1    64        // 512 f: A1_c = w_int*bn_sf/s_in
#define WS_B1    2112      // 512 f: B1_c = b_int*bn_sf
#define WS_WSC   4160      // 128 f
#define WS_XMX   4672      // 512 f: per-channel max(x)
#define WS_XMN   6720      // 512 f: per-channel min(x)
#define WS_WQ    8768      // 589824 i8: [tap][ci][cq][co128][16]
#define WS_X2    598592    // 17825792 u8: [b][h][ci][cq][w'34][16]
#define WS_ZROW  18424384  // 17408 u8 zero row
// ws_f[3] = s_act (k_xquant blk0), ws_u[1] = absmax(y) bits

__device__ __forceinline__ float wave_max(float m) {
#pragma unroll
    for (int off = 32; off; off >>= 1) m = fmaxf(m, __shfl_xor(m, off));
    return m;
}

// async global->LDS, 16B per lane: per-lane gsrc, wave-uniform LDS base
__device__ __forceinline__ void stage16(const char* g, char* s, int lane) {
#if defined(__has_builtin) && __has_builtin(__builtin_amdgcn_global_load_lds)
    __builtin_amdgcn_global_load_lds(
        (const __attribute__((address_space(1))) void*)g,
        (__attribute__((address_space(3))) void*)s, 16, 0, 0);
#else
    *(v4i*)(s + lane * 16) = *(const v4i*)g;
#endif
}

// ---- kernel 1: fused prep ---------------------------------------------------
// blocks 0..511:   per-channel x max/min (block c owns channel c)
// blocks 512..639: conv-weight quant (co = bid-512)
// block 640:       BN fold -> A1/B1, zero y-absmax
__global__ __launch_bounds__(512) void k_prep(
    const float* __restrict__ gamma, const float* __restrict__ beta,
    const float* __restrict__ mean,  const float* __restrict__ var,
    const float* __restrict__ asf,   const float* __restrict__ cw,
    const float4* __restrict__ x4,
    float* ws_f, unsigned* ws_u, float* __restrict__ wsc,
    signed char* __restrict__ wq) {
    int t = threadIdx.x;
    int bid = blockIdx.x;
    __shared__ float red[16];
    if (bid < 512) {
        int c = bid;
        float mx = -3.4e38f, mn = 3.4e38f;
#pragma unroll
        for (int r = 0; r < 16; ++r) {
            int bbb = r * 2 + (t >> 8);
            float4 v = x4[((size_t)(bbb * 512 + c)) * 256 + (t & 255)];
            mx = fmaxf(mx, fmaxf(fmaxf(v.x, v.y), fmaxf(v.z, v.w)));
            mn = fminf(mn, fminf(fminf(v.x, v.y), fminf(v.z, v.w)));
        }
        mx = wave_max(mx);
        mn = -wave_max(-mn);
        if ((t & 63) == 0) { red[t >> 6] = mx; red[8 + (t >> 6)] = mn; }
        __syncthreads();
        if (t == 0) {
            float M = red[0], N = red[8];
#pragma unroll
            for (int i = 1; i < 8; ++i) { M = fmaxf(M, red[i]); N = fminf(N, red[8 + i]); }
            ws_f[WS_XMX / 4 + c] = M;
            ws_f[WS_XMN / 4 + c] = N;
        }
    } else if (bid < 640) {
        int co = bid - 512;
        const float* w = cw + (size_t)co * 4608;
        float m = 0.f;
        for (int j = t; j < 4608; j += 512) m = fmaxf(m, fabsf(w[j]));
        m = wave_max(m);
        if ((t & 63) == 0) red[t >> 6] = m;
        __syncthreads();
        float mall = red[0];
#pragma unroll
        for (int i = 1; i < 8; ++i) mall = fmaxf(mall, red[i]);
        float sc = mall / 127.0f;
        if (t == 0) wsc[co] = sc;
        int ci = t >> 6, cq = (t >> 4) & 3, cb = t & 15;
#pragma unroll
        for (int tap = 0; tap < 9; ++tap) {
            float q = fminf(fmaxf(rintf(w[t * 9 + tap] / sc), -128.f), 127.f);
            wq[(((size_t)(tap * 8 + ci) * 4 + cq) * 128 + co) * 16 + cb] = (signed char)q;
        }
    } else {
        float wbn = gamma[t] / sqrtf(var[t] + 1e-5f);
        float bbn = beta[t] - mean[t] * wbn;
        float m = wave_max(fabsf(wbn));
        if ((t & 63) == 0) red[t >> 6] = m;
        __syncthreads();
        float mall = red[0];
#pragma unroll
        for (int i = 1; i < 8; ++i) mall = fmaxf(mall, red[i]);
        float ws_bn = mall / 127.0f;
        float s_in  = asf[0];
        float bn_sf = ws_bn * s_in;
        float wint  = fminf(fmaxf(rintf(wbn / ws_bn), -128.f), 127.f);
        float bint  = rintf(bbn / bn_sf);
        ws_f[WS_A1 / 4 + t] = wint * bn_sf / s_in;  // x1 = fmaf(x, A1, B1)
        ws_f[WS_B1 / 4 + t] = bint * bn_sf;
        if (t == 0) ws_u[1] = 0u;  // absmax(y) bits
    }
}

// ---- kernel 2: quantize x to int8 [ci][cq][w'][16] halo layout -------------
__global__ __launch_bounds__(256) void k_xquant(
    const float4* __restrict__ x4, float* __restrict__ ws_f,
    unsigned* __restrict__ x2u, unsigned* __restrict__ zrowu) {
    int bb = 31 - (blockIdx.x >> 5), h = blockIdx.x & 31;
    const float* A1 = ws_f + WS_A1 / 4;
    const float* B1 = ws_f + WS_B1 / 4;
    const float* XMX = ws_f + WS_XMX / 4;
    const float* XMN = ws_f + WS_XMN / 4;
    int t = threadIdx.x;

    // s_act from per-channel stats (exact: fma monotone in x, relu clamp >=0)
    __shared__ float sred[4];
    float cand = 0.f;
#pragma unroll
    for (int c0 = 0; c0 < 512; c0 += 256) {
        int c = c0 + t;
        float A = A1[c], B = B1[c];
        cand = fmaxf(cand, fmaxf(fmaf(XMX[c], A, B), fmaf(XMN[c], A, B)));
    }
    cand = wave_max(cand);
    if ((t & 63) == 0) sred[t >> 6] = cand;
    __syncthreads();
    float xm = fmaxf(fmaxf(sred[0], sred[1]), fmaxf(sred[2], sred[3]));
    float inv_sact = 127.0f / xm;
    if (blockIdx.x == 0 && t == 0) ws_f[3] = xm / 127.0f;  // s_act for k_conv

    size_t rowd = (size_t)(bb * 32 + h) * 4352;  // dwords per (b,h) row
    // zero halo columns w'=0,33
    {
        int p = t >> 3, side = (t >> 2) & 1, d = t & 3;
        x2u[rowd + (p * 34 + side * 33) * 4 + d] = 0u;
    }
    if (blockIdx.x < 17) {
        int idx = blockIdx.x * 256 + t;
        if (idx < 4352) zrowu[idx] = 0u;
    }

    __shared__ unsigned lds[512 * 9];  // [c][w4(8)] packed bytes, +1 pad

#pragma unroll
    for (int it = 0; it < 16; ++it) {
        int idx = it * 256 + t;
        int c = idx >> 3, f4 = idx & 7;
        float4 v = x4[((size_t)bb * 512 + c) * 256 + h * 8 + f4];
        float A = A1[c] * inv_sact, B = B1[c] * inv_sact;
        unsigned q0 = (unsigned)(int)fminf(rintf(fmaxf(fmaf(v.x, A, B), 0.f)), 127.f);
        unsigned q1 = (unsigned)(int)fminf(rintf(fmaxf(fmaf(v.y, A, B), 0.f)), 127.f);
        unsigned q2 = (unsigned)(int)fminf(rintf(fmaxf(fmaf(v.z, A, B), 0.f)), 127.f);
        unsigned q3 = (unsigned)(int)fminf(rintf(fmaxf(fmaf(v.w, A, B), 0.f)), 127.f);
        lds[c * 9 + f4] = q0 | (q1 << 8) | (q2 << 16) | (q3 << 24);
    }
    __syncthreads();

#pragma unroll
    for (int it = 0; it < 4; ++it) {
        int p = it * 8 + (t >> 5);   // 0..31 = ci*4+cq
        int s = (t >> 2) & 7;        // w4 group
        int k = t & 3;               // w = s*4+k, w' = w+1
        unsigned L[16];
#pragma unroll
        for (int j = 0; j < 16; ++j) L[j] = lds[(p * 16 + j) * 9 + s];
        uint4 o;
        unsigned* op = (unsigned*)&o;
#pragma unroll
        for (int d = 0; d < 4; ++d)
            op[d] = ((L[4 * d] >> (8 * k)) & 255u) |
                    (((L[4 * d + 1] >> (8 * k)) & 255u) << 8) |
                    (((L[4 * d + 2] >> (8 * k)) & 255u) << 16) |
                    (((L[4 * d + 3] >> (8 * k)) & 255u) << 24);
        *(uint4*)(x2u + rowd + (size_t)(p * 34 + s * 4 + 1 + k) * 4) = o;
    }
}

// ---- kernel 3: int8 3x3 conv, dbuf B, explicit register-blocked inner loop --
// block = 4 rows x 64 co, 4 waves = (rp row-pair, wh w-half);
// wave = 2 rows x 16 w x 64 co, acc[2][4] (r = row, nt = co-16-group).
// Per K-iter: stage NEXT B tile (9 gload_lds/wave) -> hoist A[4][3] (12 v4i:
// in-rows h0-1..h0+2 x 3 kw, kh-chain CSE) -> 3x { batch 12 B ds_reads,
// setprio(1), 24 MFMAs, setprio(0) } -> ONE __syncthreads.
// LDS 2x36KB=72KB -> 2 blocks/CU, 8 waves/CU.
__global__ __launch_bounds__(256, 2) void k_conv(
    const unsigned char* __restrict__ x2, const unsigned char* __restrict__ zrow,
    const signed char* __restrict__ wq,
    const float* __restrict__ wsc, const float* __restrict__ ws_f,
    unsigned* __restrict__ amaxy, float* __restrict__ y) {
    __shared__ char ldsb[73728];
    int t = threadIdx.x;
    int lane = t & 63, wv = t >> 6;
    int wh = wv & 1, rp = wv >> 1;   // w-half, row-pair
    int m = lane & 15, quad = lane >> 4;

    int bid = blockIdx.x;
    int tile = (bid & 7) * 64 + (bid >> 3);  // XCD swizzle, 64 tiles/XCD
    int ch = tile & 1;
    int rg = (tile >> 1) & 7;                // row-group of 4 rows
    int bb = tile >> 4;
    int co0 = ch * 64;
    int h0 = rg * 4 + rp * 2;                // this wave's first output row

    const unsigned char* xb = x2 + (size_t)bb * (32 * 17408);
    const v4i* rpt[4];
#pragma unroll
    for (int j = 0; j < 4; ++j) {
        int row = h0 - 1 + j;
        rpt[j] = (const v4i*)(((unsigned)row < 32u) ? (xb + (size_t)row * 17408) : zrow);
    }

    v4i acc[2][4];
#pragma unroll
    for (int i = 0; i < 2; ++i)
#pragma unroll
        for (int j = 0; j < 4; ++j) acc[i][j] = (v4i){0, 0, 0, 0};

    int abase = quad * 34 + m + wh * 16;  // [cq=quad][w'=m+wh*16] in v4i units

    // prologue: stage ci=0 into buffer 0 (36 x 1KB chunks, 9 per wave)
#pragma unroll
    for (int i = 0; i < 9; ++i) {
        int c = wv * 9 + i;
        int tap = c >> 2, cq = c & 3;
        const char* g = (const char*)wq +
            ((((size_t)(tap * 8 + 0) * 4 + cq) * 128 + co0) * 16) + lane * 16;
        stage16(g, ldsb + (c << 10), lane);
    }
    __syncthreads();

#pragma unroll
    for (int ci = 0; ci < 8; ++ci) {
        // stage NEXT ci-group into the other buffer (latency hides under MFMA)
        if (ci < 7) {
#pragma unroll
            for (int i = 0; i < 9; ++i) {
                int c = wv * 9 + i;
                int tap = c >> 2, cq = c & 3;
                const char* g = (const char*)wq +
                    ((((size_t)(tap * 8 + ci + 1) * 4 + cq) * 128 + co0) * 16) + lane * 16;
                stage16(g, ldsb + ((ci + 1) & 1) * 36864 + (c << 10), lane);
            }
        }
        const v4i* bv = (const v4i*)(ldsb + (ci & 1) * 36864);

        // hoist ALL A-fragments for this iter: in-rows h0-1..h0+2 x 3 kw.
        // (48 VGPR; exposes the 12 independent global loads to the scheduler)
        v4i A[4][3];
#pragma unroll
        for (int r = 0; r < 4; ++r)
#pragma unroll
            for (int kw = 0; kw < 3; ++kw)
                A[r][kw] = rpt[r][ci * 136 + abase + kw];

#pragma unroll
        for (int kh = 0; kh < 3; ++kh) {
            // batch 12 B-fragment ds_reads (48 VGPR), then a pure-MFMA cluster
            v4i B[3][4];
#pragma unroll
            for (int kw = 0; kw < 3; ++kw)
#pragma unroll
                for (int nt = 0; nt < 4; ++nt)
                    B[kw][nt] = bv[((kh * 3 + kw) * 4 + quad) * 64 + nt * 16 + m];
            __builtin_amdgcn_s_setprio(1);
#pragma unroll
            for (int kw = 0; kw < 3; ++kw)
#pragma unroll
                for (int nt = 0; nt < 4; ++nt) {
                    acc[0][nt] = __builtin_amdgcn_mfma_i32_16x16x64_i8(
                        A[kh][kw], B[kw][nt], acc[0][nt], 0, 0, 0);
                    acc[1][nt] = __builtin_amdgcn_mfma_i32_16x16x64_i8(
                        A[kh + 1][kw], B[kw][nt], acc[1][nt], 0, 0, 0);
                }
            __builtin_amdgcn_s_setprio(0);
        }
        __syncthreads();  // cur reads done by all waves + next-buf stages drained
    }

    // epilogue: C layout col(lane&15)=co, row(quad*4+reg)=w-within-half.
    // y unquantized; track block absmax -> one atomicMax per block.
    float s_act = ws_f[3];
    float mx = 0.f;
#pragma unroll
    for (int nt = 0; nt < 4; ++nt) {
        int co = co0 + nt * 16 + m;
        float sf = s_act * wsc[co];
#pragma unroll
        for (int r = 0; r < 2; ++r) {
            int row = h0 + r;
            float* yb = y + ((size_t)(bb * 128 + co)) * 1024 + row * 32 + wh * 16;
            float4 vv;
            vv.x = (float)acc[r][nt][0] * sf;
            vv.y = (float)acc[r][nt][1] * sf;
            vv.z = (float)acc[r][nt][2] * sf;
            vv.w = (float)acc[r][nt][3] * sf;
            *(float4*)(yb + quad * 4) = vv;
            mx = fmaxf(mx, fmaxf(fmaxf(fabsf(vv.x), fabsf(vv.y)),
                                 fmaxf(fabsf(vv.z), fabsf(vv.w))));
        }
    }
    mx = wave_max(mx);
    if (lane == 0) ((float*)ldsb)[wv] = mx;   // loop ended with __syncthreads
    __syncthreads();
    if (t == 0) {
        float* r = (float*)ldsb;
        float M = fmaxf(fmaxf(r[0], r[1]), fmaxf(r[2], r[3]));
        atomicMax(amaxy, __float_as_uint(M));
    }
}

// ---- kernel 4: final requant in place + write s_out -----------------------
__global__ __launch_bounds__(256) void k_yquant(float* __restrict__ yout,
                                                const unsigned* __restrict__ ws_u) {
    float s_out = __uint_as_float(ws_u[1]) / 127.0f;
    float4* y4 = (float4*)yout;
    int stride = gridDim.x * blockDim.x;
    for (int i = blockIdx.x * blockDim.x + threadIdx.x; i < 1048576; i += stride) {
        float4 v = y4[i];
        v.x = fminf(fmaxf(rintf(v.x / s_out), -128.f), 127.f) * s_out;
        v.y = fminf(fmaxf(rintf(v.y / s_out), -128.f), 127.f) * s_out;
        v.z = fminf(fmaxf(rintf(v.z / s_out), -128.f), 127.f) * s_out;
        v.w = fminf(fmaxf(rintf(v.w / s_out), -128.f), 127.f) * s_out;
        y4[i] = v;
    }
    if (blockIdx.x == 0 && threadIdx.x == 0) yout[4194304] = s_out;
}

extern "C" void kernel_launch(void* const* d_in, const int* in_sizes, int n_in,
                              void* d_out, int out_size, void* d_ws, size_t ws_size,
                              hipStream_t stream) {
    const float* x     = (const float*)d_in[0];
    const float* asf   = (const float*)d_in[1];
    const float* gamma = (const float*)d_in[2];
    const float* beta  = (const float*)d_in[3];
    const float* mean  = (const float*)d_in[4];
    const float* var   = (const float*)d_in[5];
    const float* cw    = (const float*)d_in[6];

    float*    ws_f = (float*)d_ws;
    unsigned* ws_u = (unsigned*)d_ws;
    signed char*   wq   = (signed char*)d_ws + WS_WQ;
    unsigned char* x2   = (unsigned char*)d_ws + WS_X2;
    unsigned char* zrow = (unsigned char*)d_ws + WS_ZROW;
    float* y = (float*)d_out;

    k_prep<<<641, 512, 0, stream>>>(gamma, beta, mean, var, asf, cw,
                                    (const float4*)x, ws_f, ws_u,
                                    ws_f + WS_WSC / 4, wq);
    k_xquant<<<1024, 256, 0, stream>>>((const float4*)x, ws_f,
                                       (unsigned*)x2, (unsigned*)zrow);
    k_conv<<<512, 256, 0, stream>>>(x2, zrow, wq, ws_f + WS_WSC / 4,
                                    ws_f, ws_u + 1, y);
    k_yquant<<<1024, 256, 0, stream>>>(y, ws_u);
}

// Round 6
// 151.598 us; speedup vs baseline: 1.7141x; 1.0040x over previous
//
#include <hip/hip_runtime.h>

// ---------------------------------------------------------------------------
// Q_DenseLayer: BN-fold int8 affine -> ReLU -> per-tensor 8b quant ->
// int8 3x3 conv (MFMA i32_16x16x64_i8) -> per-tensor 8b requant.
// Shapes: x[32,512,32,32] f32, W[128,512,3,3] f32, out y[32,128,32,32] + s_out.
//
// R14: un-serialize k_conv's pipes. R13 measured ~26us = sum-of-pipes; cause:
// (a) stage16s issued BEFORE A-loads -- vmcnt retires in issue order, so the
//     A-wait before kh0's MFMA drained the stages too: dbuf never hid the
//     stage latency. Fix: issue A-loads FIRST (A-wait = vmcnt(9), stages stay
//     in flight until the barrier).
// (b) each kh ran ds_read x12 -> lgkmcnt(0) -> MFMA x24 in lockstep. Fix:
//     pipeline B one kh ahead (B0 preloaded; B1 issued before kh0's cluster;
//     B2 issued after it) so ds_reads overlap the MFMA clusters in-wave.
//     Static B0/B1/B2 buffers (rule: no runtime-indexed reg arrays); B2
//     aliases B0 by liveness. ~230 VGPR under (256,2).
// R13 kept: A[4][3] hoist (kh-chain CSE), setprio around MFMA clusters.
// R12 kept: dbuf B (2x36KB LDS, 2 blocks/CU), 1 barrier/iter, wave =
// 2 rows x 16 w x 64 co (A-reuse 4), grid 512 XCD-swizzled, no K-split.
// Layouts: x2 [b][h][ci8][cq4][w'34][16B], wq [tap][ci][cq4][co128][16B].
// Fixed ~95us harness work (ws poison + d_in restore) outside our control.
// ---------------------------------------------------------------------------

typedef int v4i __attribute__((ext_vector_type(4)));

// workspace byte offsets
#define WS_A1    64        // 512 f: A1_c = w_int*bn_sf/s_in
#define WS_B1    2112      // 512 f: B1_c = b_int*bn_sf
#define WS_WSC   4160      // 128 f
#define WS_XMX   4672      // 512 f: per-channel max(x)
#define WS_XMN   6720      // 512 f: per-channel min(x)
#define WS_WQ    8768      // 589824 i8: [tap][ci][cq][co128][16]
#define WS_X2    598592    // 17825792 u8: [b][h][ci][cq][w'34][16]
#define WS_ZROW  18424384  // 17408 u8 zero row
// ws_f[3] = s_act (k_xquant blk0), ws_u[1] = absmax(y) bits

__device__ __forceinline__ float wave_max(float m) {
#pragma unroll
    for (int off = 32; off; off >>= 1) m = fmaxf(m, __shfl_xor(m, off));
    return m;
}

// async global->LDS, 16B per lane: per-lane gsrc, wave-uniform LDS base
__device__ __forceinline__ void stage16(const char* g, char* s, int lane) {
#if defined(__has_builtin) && __has_builtin(__builtin_amdgcn_global_load_lds)
    __builtin_amdgcn_global_load_lds(
        (const __attribute__((address_space(1))) void*)g,
        (__attribute__((address_space(3))) void*)s, 16, 0, 0);
#else
    *(v4i*)(s + lane * 16) = *(const v4i*)g;
#endif
}

// ---- kernel 1: fused prep ---------------------------------------------------
// blocks 0..511:   per-channel x max/min (block c owns channel c)
// blocks 512..639: conv-weight quant (co = bid-512)
// block 640:       BN fold -> A1/B1, zero y-absmax
__global__ __launch_bounds__(512) void k_prep(
    const float* __restrict__ gamma, const float* __restrict__ beta,
    const float* __restrict__ mean,  const float* __restrict__ var,
    const float* __restrict__ asf,   const float* __restrict__ cw,
    const float4* __restrict__ x4,
    float* ws_f, unsigned* ws_u, float* __restrict__ wsc,
    signed char* __restrict__ wq) {
    int t = threadIdx.x;
    int bid = blockIdx.x;
    __shared__ float red[16];
    if (bid < 512) {
        int c = bid;
        float mx = -3.4e38f, mn = 3.4e38f;
#pragma unroll
        for (int r = 0; r < 16; ++r) {
            int bbb = r * 2 + (t >> 8);
            float4 v = x4[((size_t)(bbb * 512 + c)) * 256 + (t & 255)];
            mx = fmaxf(mx, fmaxf(fmaxf(v.x, v.y), fmaxf(v.z, v.w)));
            mn = fminf(mn, fminf(fminf(v.x, v.y), fminf(v.z, v.w)));
        }
        mx = wave_max(mx);
        mn = -wave_max(-mn);
        if ((t & 63) == 0) { red[t >> 6] = mx; red[8 + (t >> 6)] = mn; }
        __syncthreads();
        if (t == 0) {
            float M = red[0], N = red[8];
#pragma unroll
            for (int i = 1; i < 8; ++i) { M = fmaxf(M, red[i]); N = fminf(N, red[8 + i]); }
            ws_f[WS_XMX / 4 + c] = M;
            ws_f[WS_XMN / 4 + c] = N;
        }
    } else if (bid < 640) {
        int co = bid - 512;
        const float* w = cw + (size_t)co * 4608;
        float m = 0.f;
        for (int j = t; j < 4608; j += 512) m = fmaxf(m, fabsf(w[j]));
        m = wave_max(m);
        if ((t & 63) == 0) red[t >> 6] = m;
        __syncthreads();
        float mall = red[0];
#pragma unroll
        for (int i = 1; i < 8; ++i) mall = fmaxf(mall, red[i]);
        float sc = mall / 127.0f;
        if (t == 0) wsc[co] = sc;
        int ci = t >> 6, cq = (t >> 4) & 3, cb = t & 15;
#pragma unroll
        for (int tap = 0; tap < 9; ++tap) {
            float q = fminf(fmaxf(rintf(w[t * 9 + tap] / sc), -128.f), 127.f);
            wq[(((size_t)(tap * 8 + ci) * 4 + cq) * 128 + co) * 16 + cb] = (signed char)q;
        }
    } else {
        float wbn = gamma[t] / sqrtf(var[t] + 1e-5f);
        float bbn = beta[t] - mean[t] * wbn;
        float m = wave_max(fabsf(wbn));
        if ((t & 63) == 0) red[t >> 6] = m;
        __syncthreads();
        float mall = red[0];
#pragma unroll
        for (int i = 1; i < 8; ++i) mall = fmaxf(mall, red[i]);
        float ws_bn = mall / 127.0f;
        float s_in  = asf[0];
        float bn_sf = ws_bn * s_in;
        float wint  = fminf(fmaxf(rintf(wbn / ws_bn), -128.f), 127.f);
        float bint  = rintf(bbn / bn_sf);
        ws_f[WS_A1 / 4 + t] = wint * bn_sf / s_in;  // x1 = fmaf(x, A1, B1)
        ws_f[WS_B1 / 4 + t] = bint * bn_sf;
        if (t == 0) ws_u[1] = 0u;  // absmax(y) bits
    }
}

// ---- kernel 2: quantize x to int8 [ci][cq][w'][16] halo layout -------------
__global__ __launch_bounds__(256) void k_xquant(
    const float4* __restrict__ x4, float* __restrict__ ws_f,
    unsigned* __restrict__ x2u, unsigned* __restrict__ zrowu) {
    int bb = 31 - (blockIdx.x >> 5), h = blockIdx.x & 31;
    const float* A1 = ws_f + WS_A1 / 4;
    const float* B1 = ws_f + WS_B1 / 4;
    const float* XMX = ws_f + WS_XMX / 4;
    const float* XMN = ws_f + WS_XMN / 4;
    int t = threadIdx.x;

    // s_act from per-channel stats (exact: fma monotone in x, relu clamp >=0)
    __shared__ float sred[4];
    float cand = 0.f;
#pragma unroll
    for (int c0 = 0; c0 < 512; c0 += 256) {
        int c = c0 + t;
        float A = A1[c], B = B1[c];
        cand = fmaxf(cand, fmaxf(fmaf(XMX[c], A, B), fmaf(XMN[c], A, B)));
    }
    cand = wave_max(cand);
    if ((t & 63) == 0) sred[t >> 6] = cand;
    __syncthreads();
    float xm = fmaxf(fmaxf(sred[0], sred[1]), fmaxf(sred[2], sred[3]));
    float inv_sact = 127.0f / xm;
    if (blockIdx.x == 0 && t == 0) ws_f[3] = xm / 127.0f;  // s_act for k_conv

    size_t rowd = (size_t)(bb * 32 + h) * 4352;  // dwords per (b,h) row
    // zero halo columns w'=0,33
    {
        int p = t >> 3, side = (t >> 2) & 1, d = t & 3;
        x2u[rowd + (p * 34 + side * 33) * 4 + d] = 0u;
    }
    if (blockIdx.x < 17) {
        int idx = blockIdx.x * 256 + t;
        if (idx < 4352) zrowu[idx] = 0u;
    }

    __shared__ unsigned lds[512 * 9];  // [c][w4(8)] packed bytes, +1 pad

#pragma unroll
    for (int it = 0; it < 16; ++it) {
        int idx = it * 256 + t;
        int c = idx >> 3, f4 = idx & 7;
        float4 v = x4[((size_t)bb * 512 + c) * 256 + h * 8 + f4];
        float A = A1[c] * inv_sact, B = B1[c] * inv_sact;
        unsigned q0 = (unsigned)(int)fminf(rintf(fmaxf(fmaf(v.x, A, B), 0.f)), 127.f);
        unsigned q1 = (unsigned)(int)fminf(rintf(fmaxf(fmaf(v.y, A, B), 0.f)), 127.f);
        unsigned q2 = (unsigned)(int)fminf(rintf(fmaxf(fmaf(v.z, A, B), 0.f)), 127.f);
        unsigned q3 = (unsigned)(int)fminf(rintf(fmaxf(fmaf(v.w, A, B), 0.f)), 127.f);
        lds[c * 9 + f4] = q0 | (q1 << 8) | (q2 << 16) | (q3 << 24);
    }
    __syncthreads();

#pragma unroll
    for (int it = 0; it < 4; ++it) {
        int p = it * 8 + (t >> 5);   // 0..31 = ci*4+cq
        int s = (t >> 2) & 7;        // w4 group
        int k = t & 3;               // w = s*4+k, w' = w+1
        unsigned L[16];
#pragma unroll
        for (int j = 0; j < 16; ++j) L[j] = lds[(p * 16 + j) * 9 + s];
        uint4 o;
        unsigned* op = (unsigned*)&o;
#pragma unroll
        for (int d = 0; d < 4; ++d)
            op[d] = ((L[4 * d] >> (8 * k)) & 255u) |
                    (((L[4 * d + 1] >> (8 * k)) & 255u) << 8) |
                    (((L[4 * d + 2] >> (8 * k)) & 255u) << 16) |
                    (((L[4 * d + 3] >> (8 * k)) & 255u) << 24);
        *(uint4*)(x2u + rowd + (size_t)(p * 34 + s * 4 + 1 + k) * 4) = o;
    }
}

// ---- kernel 3: int8 3x3 conv, dbuf B, vmcnt-ordered + kh-pipelined ---------
// block = 4 rows x 64 co, 4 waves = (rp row-pair, wh w-half);
// wave = 2 rows x 16 w x 64 co, acc[2][4] (r = row, nt = co-16-group).
// Per K-iter issue order (vmcnt retires in issue order!):
//   A-loads x12 -> B0,B1 ds_reads -> stage16 x9 (next buf) ->
//   MFMA kh0 (A-wait = vmcnt(9): stages stay in flight) -> B2 ds_reads ->
//   MFMA kh1 -> MFMA kh2 -> ONE __syncthreads (drains stages, had full iter).
// ds_reads of kh+1 overlap the MFMA cluster of kh (in-wave ILP).
// LDS 2x36KB=72KB -> 2 blocks/CU, 8 waves/CU.
__global__ __launch_bounds__(256, 2) void k_conv(
    const unsigned char* __restrict__ x2, const unsigned char* __restrict__ zrow,
    const signed char* __restrict__ wq,
    const float* __restrict__ wsc, const float* __restrict__ ws_f,
    unsigned* __restrict__ amaxy, float* __restrict__ y) {
    __shared__ char ldsb[73728];
    int t = threadIdx.x;
    int lane = t & 63, wv = t >> 6;
    int wh = wv & 1, rp = wv >> 1;   // w-half, row-pair
    int m = lane & 15, quad = lane >> 4;

    int bid = blockIdx.x;
    int tile = (bid & 7) * 64 + (bid >> 3);  // XCD swizzle, 64 tiles/XCD
    int ch = tile & 1;
    int rg = (tile >> 1) & 7;                // row-group of 4 rows
    int bb = tile >> 4;
    int co0 = ch * 64;
    int h0 = rg * 4 + rp * 2;                // this wave's first output row

    const unsigned char* xb = x2 + (size_t)bb * (32 * 17408);
    const v4i* rpt[4];
#pragma unroll
    for (int j = 0; j < 4; ++j) {
        int row = h0 - 1 + j;
        rpt[j] = (const v4i*)(((unsigned)row < 32u) ? (xb + (size_t)row * 17408) : zrow);
    }

    v4i acc[2][4];
#pragma unroll
    for (int i = 0; i < 2; ++i)
#pragma unroll
        for (int j = 0; j < 4; ++j) acc[i][j] = (v4i){0, 0, 0, 0};

    int abase = quad * 34 + m + wh * 16;  // [cq=quad][w'=m+wh*16] in v4i units

    // prologue: stage ci=0 into buffer 0 (36 x 1KB chunks, 9 per wave)
#pragma unroll
    for (int i = 0; i < 9; ++i) {
        int c = wv * 9 + i;
        int tap = c >> 2, cq = c & 3;
        const char* g = (const char*)wq +
            ((((size_t)(tap * 8 + 0) * 4 + cq) * 128 + co0) * 16) + lane * 16;
        stage16(g, ldsb + (c << 10), lane);
    }
    __syncthreads();

#pragma unroll
    for (int ci = 0; ci < 8; ++ci) {
        const v4i* bv = (const v4i*)(ldsb + (ci & 1) * 36864);

        // (1) A-loads FIRST: 12 global loads occupy the oldest vmcnt slots,
        // so the pre-MFMA A-wait is vmcnt(9) and leaves stages in flight.
        v4i A[4][3];
#pragma unroll
        for (int r = 0; r < 4; ++r)
#pragma unroll
            for (int kw = 0; kw < 3; ++kw)
                A[r][kw] = rpt[r][ci * 136 + abase + kw];

        auto load_B = [&](v4i(&B)[3][4], int kh) {
#pragma unroll
            for (int kw = 0; kw < 3; ++kw)
#pragma unroll
                for (int nt = 0; nt < 4; ++nt)
                    B[kw][nt] = bv[((kh * 3 + kw) * 4 + quad) * 64 + nt * 16 + m];
        };
        auto mfma_kh = [&](const v4i(&Ar0)[3], const v4i(&Ar1)[3],
                           const v4i(&B)[3][4]) {
            __builtin_amdgcn_s_setprio(1);
#pragma unroll
            for (int kw = 0; kw < 3; ++kw)
#pragma unroll
                for (int nt = 0; nt < 4; ++nt) {
                    acc[0][nt] = __builtin_amdgcn_mfma_i32_16x16x64_i8(
                        Ar0[kw], B[kw][nt], acc[0][nt], 0, 0, 0);
                    acc[1][nt] = __builtin_amdgcn_mfma_i32_16x16x64_i8(
                        Ar1[kw], B[kw][nt], acc[1][nt], 0, 0, 0);
                }
            __builtin_amdgcn_s_setprio(0);
        };

        // (2) B0 + B1 ds_reads up front (kh-pipeline depth 1)
        v4i B0[3][4], B1[3][4], B2[3][4];
        load_B(B0, 0);
        load_B(B1, 1);

        // (3) stage NEXT ci-group (9 global_load_lds) -- after A in vmcnt order
        if (ci < 7) {
#pragma unroll
            for (int i = 0; i < 9; ++i) {
                int c = wv * 9 + i;
                int tap = c >> 2, cq = c & 3;
                const char* g = (const char*)wq +
                    ((((size_t)(tap * 8 + ci + 1) * 4 + cq) * 128 + co0) * 16) + lane * 16;
                stage16(g, ldsb + ((ci + 1) & 1) * 36864 + (c << 10), lane);
            }
        }

        // (4..7) MFMA kh0 | issue B2 | MFMA kh1 | MFMA kh2
        mfma_kh(A[0], A[1], B0);
        load_B(B2, 2);
        mfma_kh(A[1], A[2], B1);
        mfma_kh(A[2], A[3], B2);

        __syncthreads();  // cur reads done by all waves + next-buf stages drained
    }

    // epilogue: C layout col(lane&15)=co, row(quad*4+reg)=w-within-half.
    // y unquantized; track block absmax -> one atomicMax per block.
    float s_act = ws_f[3];
    float mx = 0.f;
#pragma unroll
    for (int nt = 0; nt < 4; ++nt) {
        int co = co0 + nt * 16 + m;
        float sf = s_act * wsc[co];
#pragma unroll
        for (int r = 0; r < 2; ++r) {
            int row = h0 + r;
            float* yb = y + ((size_t)(bb * 128 + co)) * 1024 + row * 32 + wh * 16;
            float4 vv;
            vv.x = (float)acc[r][nt][0] * sf;
            vv.y = (float)acc[r][nt][1] * sf;
            vv.z = (float)acc[r][nt][2] * sf;
            vv.w = (float)acc[r][nt][3] * sf;
            *(float4*)(yb + quad * 4) = vv;
            mx = fmaxf(mx, fmaxf(fmaxf(fabsf(vv.x), fabsf(vv.y)),
                                 fmaxf(fabsf(vv.z), fabsf(vv.w))));
        }
    }
    mx = wave_max(mx);
    if (lane == 0) ((float*)ldsb)[wv] = mx;   // loop ended with __syncthreads
    __syncthreads();
    if (t == 0) {
        float* r = (float*)ldsb;
        float M = fmaxf(fmaxf(r[0], r[1]), fmaxf(r[2], r[3]));
        atomicMax(amaxy, __float_as_uint(M));
    }
}

// ---- kernel 4: final requant in place + write s_out -----------------------
__global__ __launch_bounds__(256) void k_yquant(float* __restrict__ yout,
                                                const unsigned* __restrict__ ws_u) {
    float s_out = __uint_as_float(ws_u[1]) / 127.0f;
    float4* y4 = (float4*)yout;
    int stride = gridDim.x * blockDim.x;
    for (int i = blockIdx.x * blockDim.x + threadIdx.x; i < 1048576; i += stride) {
        float4 v = y4[i];
        v.x = fminf(fmaxf(rintf(v.x / s_out), -128.f), 127.f) * s_out;
        v.y = fminf(fmaxf(rintf(v.y / s_out), -128.f), 127.f) * s_out;
        v.z = fminf(fmaxf(rintf(v.z / s_out), -128.f), 127.f) * s_out;
        v.w = fminf(fmaxf(rintf(v.w / s_out), -128.f), 127.f) * s_out;
        y4[i] = v;
    }
    if (blockIdx.x == 0 && threadIdx.x == 0) yout[4194304] = s_out;
}

extern "C" void kernel_launch(void* const* d_in, const int* in_sizes, int n_in,
                              void* d_out, int out_size, void* d_ws, size_t ws_size,
                              hipStream_t stream) {
    const float* x     = (const float*)d_in[0];
    const float* asf   = (const float*)d_in[1];
    const float* gamma = (const float*)d_in[2];
    const float* beta  = (const float*)d_in[3];
    const float* mean  = (const float*)d_in[4];
    const float* var   = (const float*)d_in[5];
    const float* cw    = (const float*)d_in[6];

    float*    ws_f = (float*)d_ws;
    unsigned* ws_u = (unsigned*)d_ws;
    signed char*   wq   = (signed char*)d_ws + WS_WQ;
    unsigned char* x2   = (unsigned char*)d_ws + WS_X2;
    unsigned char* zrow = (unsigned char*)d_ws + WS_ZROW;
    float* y = (float*)d_out;

    k_prep<<<641, 512, 0, stream>>>(gamma, beta, mean, var, asf, cw,
                                    (const float4*)x, ws_f, ws_u,
                                    ws_f + WS_WSC / 4, wq);
    k_xquant<<<1024, 256, 0, stream>>>((const float4*)x, ws_f,
                                       (unsigned*)x2, (unsigned*)zrow);
    k_conv<<<512, 256, 0, stream>>>(x2, zrow, wq, ws_f + WS_WSC / 4,
                                    ws_f, ws_u + 1, y);
    k_yquant<<<1024, 256, 0, stream>>>(y, ws_u);
}